// Round 1
// baseline (5724.634 us; speedup 1.0000x reference)
//
#include <hip/hip_runtime.h>
#include <math.h>

#define EPSB 1e-5f

__device__ __forceinline__ float fsig(float x){ x = fminf(fmaxf(x,-30.f),30.f); return 1.f/(1.f+__expf(-x)); }
__device__ __forceinline__ float ftanh(float x){ x = fminf(fmaxf(x,-15.f),15.f); float t = __expf(2.f*x); return (t-1.f)/(t+1.f); }

// ---------------- transpose: dst[c*R+r] = src[r*C+c] ----------------
__global__ __launch_bounds__(256) void k_transpose(float* __restrict__ dst, const float* __restrict__ src, int R, int C){
  int t = blockIdx.x*256 + threadIdx.x;
  if (t >= R*C) return;
  int r = t / C, c = t - r*C;
  dst[c*R + r] = src[t];
}

// ---------------- embedding: tE[b][ch][l] = emb[idx[b][l]][ch] ----------------
__global__ __launch_bounds__(256) void k_embed(float* __restrict__ tE, const float* __restrict__ emb, const int* __restrict__ idx){
  int t = blockIdx.x*256 + threadIdx.x;   // < 64*128*32
  int b = t >> 12, r = t & 4095, ch = r >> 5, l = r & 31;
  tE[t] = emb[idx[b*32 + l]*128 + ch];
}

// ---------------- text conv1d (k=3, pad=1) + relu ----------------
// in [64][Cin][32], w [Cout][Cin][3], out [64][Cout][32]
__global__ __launch_bounds__(256) void k_conv1d(const float* __restrict__ in, const float* __restrict__ w,
    const float* __restrict__ bias, float* __restrict__ out, int Cin, int Cout){
  __shared__ float inL[8192];
  int b = blockIdx.y, tid = threadIdx.x;
  int n = Cin*32;
  for (int i = tid; i < n; i += 256) inL[i] = in[(size_t)b*n + i];
  __syncthreads();
  int u = blockIdx.x*256 + tid;     // < Cout*4
  int co = u >> 2, l0 = (u & 3)*8;
  float acc[8];
  #pragma unroll
  for (int l = 0; l < 8; ++l) acc[l] = 0.f;
  for (int ci = 0; ci < Cin; ++ci){
    float rin[10];
    #pragma unroll
    for (int ii = 0; ii < 10; ++ii){
      int p = l0 - 1 + ii;
      rin[ii] = (p >= 0 && p < 32) ? inL[ci*32 + p] : 0.f;
    }
    const float* wp = w + ((size_t)co*Cin + ci)*3;
    float w0 = wp[0], w1 = wp[1], w2 = wp[2];
    #pragma unroll
    for (int l = 0; l < 8; ++l) acc[l] += rin[l]*w0 + rin[l+1]*w1 + rin[l+2]*w2;
  }
  float bb = bias ? bias[co] : 0.f;
  #pragma unroll
  for (int l = 0; l < 8; ++l){
    float v = acc[l] + bb;
    out[((size_t)b*Cout + co)*32 + l0 + l] = v > 0.f ? v : 0.f;
  }
}

// ---------------- text bn (per-channel over B*L=2048), in place ----------------
__global__ __launch_bounds__(256) void k_bn_text(float* __restrict__ x, const float* __restrict__ g, const float* __restrict__ be, int C){
  __shared__ float s1[256], s2[256];
  __shared__ float sc[2];
  int c = blockIdx.x, tid = threadIdx.x;
  float sum = 0.f, ss = 0.f;
  for (int i = tid; i < 2048; i += 256){
    int b = i >> 5, l = i & 31;
    float v = x[((size_t)b*C + c)*32 + l];
    sum += v; ss += v*v;
  }
  s1[tid] = sum; s2[tid] = ss;
  __syncthreads();
  for (int off = 128; off; off >>= 1){
    if (tid < off){ s1[tid] += s1[tid+off]; s2[tid] += s2[tid+off]; }
    __syncthreads();
  }
  if (tid == 0){
    float mean = s1[0]*(1.f/2048.f);
    float var  = s2[0]*(1.f/2048.f) - mean*mean;
    float rs = rsqrtf(var + EPSB);
    sc[0] = g[c]*rs;
    sc[1] = be[c] - mean*g[c]*rs;
  }
  __syncthreads();
  float a = sc[0], bsh = sc[1];
  for (int i = tid; i < 2048; i += 256){
    int b = i >> 5, l = i & 31;
    size_t o = ((size_t)b*C + c)*32 + l;
    x[o] = x[o]*a + bsh;
  }
}

// ---------------- conv bn: partial sums (atomic) + finalize ----------------
__global__ __launch_bounds__(256) void k_bn_partial(const float* __restrict__ x, float* __restrict__ sums, int C, int S, int split){
  __shared__ float s1[256], s2[256];
  int c = blockIdx.x / split, chunk = blockIdx.x - c*split;
  int tid = threadIdx.x;
  int n = 64*S, per = n/split, i0 = chunk*per;
  float sum = 0.f, ss = 0.f;
  for (int i = i0 + tid; i < i0 + per; i += 256){
    int b = i / S, s = i - b*S;
    float v = x[((size_t)b*C + c)*S + s];
    sum += v; ss += v*v;
  }
  s1[tid] = sum; s2[tid] = ss;
  __syncthreads();
  for (int off = 128; off; off >>= 1){
    if (tid < off){ s1[tid] += s1[tid+off]; s2[tid] += s2[tid+off]; }
    __syncthreads();
  }
  if (tid == 0){
    atomicAdd(&sums[c], s1[0]);
    atomicAdd(&sums[C + c], s2[0]);
  }
}

__global__ void k_bn_finalize(const float* __restrict__ sums, const float* __restrict__ g, const float* __restrict__ be,
    float* __restrict__ scale, float* __restrict__ shift, int C, int S){
  int c = blockIdx.x*64 + threadIdx.x;
  if (c >= C) return;
  float n = 64.f*(float)S;
  float mean = sums[c]/n;
  float var  = sums[C+c]/n - mean*mean;
  float rs = rsqrtf(var + EPSB);
  scale[c] = g[c]*rs;
  shift[c] = be[c] - mean*g[c]*rs;
}

// ---------------- conv1: (64,4,32^3) -> (64,64,16^3), stride2 pad1 k3, relu ----------------
__global__ __launch_bounds__(256) void k_conv1(const float* __restrict__ in, const float* __restrict__ w,
    const float* __restrict__ bias, float* __restrict__ out){
  // grid (16 z, 64 co, 64 b), block 256 = 16y x 16x
  __shared__ float inT[12*32*33];   // [ci*3+zz][iy][ix pad33]
  __shared__ float wT[108];
  int z = blockIdx.x, co = blockIdx.y, b = blockIdx.z, tid = threadIdx.x;
  if (tid < 108) wT[tid] = w[co*108 + tid];
  for (int i = tid; i < 12288; i += 256){
    int q = i >> 10;              // ci*3+zz
    int p = i & 1023;
    int ci = q/3, zz = q - ci*3;
    int iz = 2*z - 1 + zz;
    float v = (iz >= 0 && iz < 32) ? in[(((size_t)b*4 + ci)*32 + iz)*1024 + p] : 0.f;
    inT[(q*32 + (p >> 5))*33 + (p & 31)] = v;
  }
  __syncthreads();
  int ty = tid >> 4, tx = tid & 15;
  float acc = 0.f;
  for (int ci = 0; ci < 4; ++ci){
    #pragma unroll
    for (int dz = 0; dz < 3; ++dz){
      #pragma unroll
      for (int dy = 0; dy < 3; ++dy){
        int iy = 2*ty - 1 + dy;
        if (iy < 0) continue;
        #pragma unroll
        for (int dx = 0; dx < 3; ++dx){
          int ix = 2*tx - 1 + dx;
          if (ix < 0) continue;
          acc += inT[((ci*3+dz)*32 + iy)*33 + ix]*wT[ci*27 + dz*9 + dy*3 + dx];
        }
      }
    }
  }
  float v = acc + bias[co];
  out[(((size_t)b*64 + co)*16 + z)*256 + tid] = v > 0.f ? v : 0.f;
}

// ---------------- conv2: (64,64,16^3)->(64,128,8^3); bn1 affine applied on load ----------------
__global__ __launch_bounds__(512) void k_conv2(const float* __restrict__ x1, const float* __restrict__ w,
    const float* __restrict__ bias, const float* __restrict__ scale, const float* __restrict__ shift,
    float* __restrict__ out){
  // grid (8 z, 16 cog, 64 b), block 512 = 8co x 64yx
  __shared__ float inT[48*16*17];   // [ci*3+zz][iy][ix pad17], ci-chunk 16
  __shared__ float wT[3456];        // [cl8][ci16][27]
  int z = blockIdx.x, cog = blockIdx.y, b = blockIdx.z, tid = threadIdx.x;
  int cl = tid >> 6, yx = tid & 63, y = yx >> 3, xx = yx & 7;
  float acc = 0.f;
  for (int ci0 = 0; ci0 < 64; ci0 += 16){
    __syncthreads();
    for (int i = tid; i < 12288; i += 512){
      int q = i >> 8;             // ci*3+zz (0..47)
      int p = i & 255;
      int ci = q/3, zz = q - ci*3;
      int iz = 2*z - 1 + zz;
      int cc = ci0 + ci;
      float v = 0.f;
      if (iz >= 0 && iz < 16)
        v = x1[(((size_t)b*64 + cc)*16 + iz)*256 + p]*scale[cc] + shift[cc];
      inT[(q*16 + (p >> 4))*17 + (p & 15)] = v;
    }
    for (int i = tid; i < 3456; i += 512){
      int cl2 = i/432, r = i - cl2*432;
      int ci = r/27, tap = r - ci*27;
      wT[i] = w[(((size_t)cog*8 + cl2)*64 + ci0 + ci)*27 + tap];
    }
    __syncthreads();
    for (int ci = 0; ci < 16; ++ci){
      const float* ip = &inT[ci*816];
      const float* wp = &wT[cl*432 + ci*27];
      #pragma unroll
      for (int dz = 0; dz < 3; ++dz){
        #pragma unroll
        for (int dy = 0; dy < 3; ++dy){
          int iy = 2*y - 1 + dy;
          if (iy < 0) continue;
          #pragma unroll
          for (int dx = 0; dx < 3; ++dx){
            int ix = 2*xx - 1 + dx;
            if (ix < 0) continue;
            acc += ip[(dz*16 + iy)*17 + ix]*wp[dz*9 + dy*3 + dx];
          }
        }
      }
    }
  }
  int co = cog*8 + cl;
  float v = acc + bias[co];
  out[(((size_t)b*128 + co)*8 + z)*64 + yx] = v > 0.f ? v : 0.f;
}

// ---------------- conv3: (64,128,8^3)->(64,256,4^3); bn2 affine on load ----------------
__global__ __launch_bounds__(512) void k_conv3(const float* __restrict__ x2, const float* __restrict__ w,
    const float* __restrict__ bias, const float* __restrict__ scale, const float* __restrict__ shift,
    float* __restrict__ out){
  // grid (32 cog, 64 b), block 512 = 8co x 64 pos(4^3)
  __shared__ float inT[32*576];   // [ci32][iz8][iy8][ix pad9]
  __shared__ float wT[6912];      // [cl8][ci32][27]
  int cog = blockIdx.x, b = blockIdx.y, tid = threadIdx.x;
  int cl = tid >> 6, s = tid & 63;
  int z = s >> 4, y = (s >> 2) & 3, xx = s & 3;
  float acc = 0.f;
  for (int ci0 = 0; ci0 < 128; ci0 += 32){
    __syncthreads();
    for (int i = tid; i < 16384; i += 512){
      int ci = i >> 9, p = i & 511;
      int cc = ci0 + ci;
      float v = x2[((size_t)b*128 + cc)*512 + p]*scale[cc] + shift[cc];
      inT[ci*576 + (p >> 6)*72 + ((p >> 3) & 7)*9 + (p & 7)] = v;
    }
    for (int i = tid; i < 6912; i += 512){
      int cl2 = i/864, r = i - cl2*864;
      int ci = r/27, tap = r - ci*27;
      wT[i] = w[(((size_t)cog*8 + cl2)*128 + ci0 + ci)*27 + tap];
    }
    __syncthreads();
    for (int ci = 0; ci < 32; ++ci){
      const float* ip = &inT[ci*576];
      const float* wp = &wT[cl*864 + ci*27];
      #pragma unroll
      for (int dz = 0; dz < 3; ++dz){
        int iz = 2*z - 1 + dz;
        if (iz < 0) continue;
        #pragma unroll
        for (int dy = 0; dy < 3; ++dy){
          int iy = 2*y - 1 + dy;
          if (iy < 0) continue;
          #pragma unroll
          for (int dx = 0; dx < 3; ++dx){
            int ix = 2*xx - 1 + dx;
            if (ix < 0) continue;
            acc += ip[iz*72 + iy*9 + ix]*wp[dz*9 + dy*3 + dx];
          }
        }
      }
    }
  }
  int co = cog*8 + cl;
  float v = acc + bias[co];
  out[((size_t)b*256 + co)*64 + s] = v > 0.f ? v : 0.f;
}

// ---------------- bn3 apply in place on V (64,256,64) ----------------
__global__ __launch_bounds__(256) void k_bn_apply(float* __restrict__ x, const float* __restrict__ scale, const float* __restrict__ shift){
  int i = blockIdx.x*256 + threadIdx.x;
  int c = (i >> 6) & 255;
  x[i] = x[i]*scale[c] + shift[c];
}

// ---------------- x-projections: xih = x@wihT + bih+bhh ; xg = x@wxgT + bxg+bhg ----------------
__global__ __launch_bounds__(256) void k_xproj(const float* __restrict__ tD,
    const float* __restrict__ wihT, const float* __restrict__ wxgT,
    const float* __restrict__ bih, const float* __restrict__ bhh,
    const float* __restrict__ bxg, const float* __restrict__ bhg,
    float* __restrict__ xih, float* __restrict__ xg){
  __shared__ float xr[8][256];
  int b = blockIdx.x >> 2, t0 = (blockIdx.x & 3)*8, tid = threadIdx.x;
  for (int i = tid; i < 2048; i += 256){
    int tt = i >> 8, c = i & 255;
    xr[tt][c] = tD[((size_t)b*256 + c)*32 + t0 + tt];
  }
  __syncthreads();
  float4 bi = ((const float4*)bih)[tid];
  float4 b2 = ((const float4*)bhh)[tid];
  float4 binit = make_float4(bi.x+b2.x, bi.y+b2.y, bi.z+b2.z, bi.w+b2.w);
  float4 a[8];
  #pragma unroll
  for (int tt = 0; tt < 8; ++tt) a[tt] = binit;
  const float4* Wq = (const float4*)wihT;
  for (int k = 0; k < 256; ++k){
    float4 w = Wq[k*256 + tid];
    #pragma unroll
    for (int tt = 0; tt < 8; ++tt){
      float xv = xr[tt][k];
      a[tt].x += xv*w.x; a[tt].y += xv*w.y; a[tt].z += xv*w.z; a[tt].w += xv*w.w;
    }
  }
  #pragma unroll
  for (int tt = 0; tt < 8; ++tt)
    ((float4*)xih)[((size_t)(b*32 + t0 + tt))*256 + tid] = a[tt];
  if (tid < 64){
    float4 bg = ((const float4*)bxg)[tid];
    float4 bg2 = ((const float4*)bhg)[tid];
    float4 ginit = make_float4(bg.x+bg2.x, bg.y+bg2.y, bg.z+bg2.z, bg.w+bg2.w);
    float4 g[8];
    #pragma unroll
    for (int tt = 0; tt < 8; ++tt) g[tt] = ginit;
    const float4* Wg = (const float4*)wxgT;
    for (int k = 0; k < 256; ++k){
      float4 w = Wg[k*64 + tid];
      #pragma unroll
      for (int tt = 0; tt < 8; ++tt){
        float xv = xr[tt][k];
        g[tt].x += xv*w.x; g[tt].y += xv*w.y; g[tt].z += xv*w.z; g[tt].w += xv*w.w;
      }
    }
    #pragma unroll
    for (int tt = 0; tt < 8; ++tt)
      ((float4*)xg)[((size_t)(b*32 + t0 + tt))*64 + tid] = g[tt];
  }
}

// ---------------- vproj[b][n][o] = sum_c V[b][c][n]*wvT[c][o] + bv[o] ----------------
__global__ __launch_bounds__(512) void k_vproj(const float* __restrict__ V, const float* __restrict__ wvT,
    const float* __restrict__ bv, float* __restrict__ vproj){
  // grid (8 ngroup, 64 b)
  __shared__ float Vc[8][256];
  int n0 = blockIdx.x*8, b = blockIdx.y, tid = threadIdx.x;
  for (int i = tid; i < 2048; i += 512){
    int nn = i >> 8, c = i & 255;
    Vc[nn][c] = V[((size_t)b*256 + c)*64 + n0 + nn];
  }
  __syncthreads();
  float acc[8];
  float bb = bv[tid];
  #pragma unroll
  for (int nn = 0; nn < 8; ++nn) acc[nn] = bb;
  for (int k = 0; k < 256; ++k){
    float w = wvT[k*512 + tid];
    #pragma unroll
    for (int nn = 0; nn < 8; ++nn) acc[nn] += Vc[nn][k]*w;
  }
  #pragma unroll
  for (int nn = 0; nn < 8; ++nn)
    vproj[((size_t)(b*64 + n0 + nn))*512 + tid] = acc[nn];
}

// ---------------- the recurrent attention scan: one workgroup per batch row ----------------
__global__ __launch_bounds__(1024) void k_scan(
    const float* __restrict__ V,
    const float* __restrict__ vproj,
    const float* __restrict__ xih,
    const float* __restrict__ xg,
    const float* __restrict__ whhT,
    const float* __restrict__ whgT,
    const float* __restrict__ whT,
    const float* __restrict__ wsT,
    const float* __restrict__ bh,
    const float* __restrict__ bs,
    const float* __restrict__ wo,
    const float* __restrict__ bo,
    const float* __restrict__ sow, const float* __restrict__ sob,
    const float* __restrict__ tow1, const float* __restrict__ tob1,
    const float* __restrict__ tow2, const float* __restrict__ tob2,
    float* __restrict__ out)
{
  __shared__ float VL[16384];                 // [n][c]
  __shared__ __align__(16) float gatesL[1024];
  __shared__ __align__(16) float hgL[256];
  __shared__ float hL[256], hnewL[256], sentL[256];
  __shared__ __align__(16) float hpL[512], spL[512];
  __shared__ float red[1536];
  __shared__ float zf[64], psz[16], wL[65];
  __shared__ float woL[512];
  __shared__ float ctxmL[256], tmpL[256];

  int b = blockIdx.x, tid = threadIdx.x;
  for (int i = tid; i < 16384; i += 1024){
    int c = i >> 6, n2 = i & 63;
    VL[n2*256 + c] = V[((size_t)b*256 + c)*64 + n2];
  }
  if (tid < 512) woL[tid] = wo[tid];
  if (tid < 256) hL[tid] = 0.f;
  float creg = 0.f, ctxsum = 0.f;
  float bo0 = bo[0];
  __syncthreads();

  for (int t = 0; t < 32; ++t){
    // A: gates = xih + h@whhT (4 outs/thread); hg = xg + h@whgT
    if (tid < 256){
      float4 acc = ((const float4*)(xih + ((size_t)(b*32 + t))*1024))[tid];
      const float4* Wq = (const float4*)whhT;
      #pragma unroll 4
      for (int k = 0; k < 256; ++k){
        float hk = hL[k];
        float4 w = Wq[k*256 + tid];
        acc.x += hk*w.x; acc.y += hk*w.y; acc.z += hk*w.z; acc.w += hk*w.w;
      }
      ((float4*)gatesL)[tid] = acc;
    } else if (tid < 320){
      int j = tid - 256;
      float4 acc = ((const float4*)(xg + ((size_t)(b*32 + t))*256))[j];
      const float4* Wq = (const float4*)whgT;
      #pragma unroll 4
      for (int k = 0; k < 256; ++k){
        float hk = hL[k];
        float4 w = Wq[k*64 + j];
        acc.x += hk*w.x; acc.y += hk*w.y; acc.z += hk*w.z; acc.w += hk*w.w;
      }
      ((float4*)hgL)[j] = acc;
    }
    __syncthreads();
    // B: LSTM cell elementwise (i,f,g,o order)
    if (tid < 256){
      float i_ = fsig(gatesL[tid]);
      float f_ = fsig(gatesL[256 + tid]);
      float g_ = ftanh(gatesL[512 + tid]);
      float o_ = fsig(gatesL[768 + tid]);
      float cn = f_*creg + i_*g_;
      creg = cn;
      float tc = ftanh(cn);
      hnewL[tid] = o_*tc;
      sentL[tid] = fsig(hgL[tid])*tc;
    }
    __syncthreads();
    // C: hp = h_new@whT + bh ; sp = sent@wsT + bs
    if (tid < 128){
      float4 acc = ((const float4*)bh)[tid];
      const float4* Wq = (const float4*)whT;
      #pragma unroll 4
      for (int k = 0; k < 256; ++k){
        float hk = hnewL[k];
        float4 w = Wq[k*128 + tid];
        acc.x += hk*w.x; acc.y += hk*w.y; acc.z += hk*w.z; acc.w += hk*w.w;
      }
      ((float4*)hpL)[tid] = acc;
    } else if (tid < 256){
      int j = tid - 128;
      float4 acc = ((const float4*)bs)[j];
      const float4* Wq = (const float4*)wsT;
      #pragma unroll 4
      for (int k = 0; k < 256; ++k){
        float sk = sentL[k];
        float4 w = Wq[k*128 + j];
        acc.x += sk*w.x; acc.y += sk*w.y; acc.z += sk*w.z; acc.w += sk*w.w;
      }
      ((float4*)spL)[j] = acc;
    }
    __syncthreads();
    // D: z partials (16 threads per n) and sz partials
    {
      int n2 = tid >> 4, seg = tid & 15;
      const float* vp = vproj + ((size_t)(b*64 + n2))*512 + seg*32;
      float a = 0.f;
      #pragma unroll 4
      for (int o = 0; o < 32; ++o){
        int oo = seg*32 + o;
        a += ftanh(vp[o] + hpL[oo])*woL[oo];
      }
      red[tid] = a;
    }
    if (tid < 512)
      red[1024 + tid] = ftanh(spL[tid] + hpL[tid])*woL[tid];
    __syncthreads();
    // E1: fold partials
    if (tid < 64){
      float s = 0.f;
      #pragma unroll
      for (int i = 0; i < 16; ++i) s += red[tid*16 + i];
      zf[tid] = s + bo0;
    } else if (tid < 80){
      float s = 0.f;
      #pragma unroll
      for (int i = 0; i < 32; ++i) s += red[1024 + (tid-64)*32 + i];
      psz[tid - 64] = s;
    }
    __syncthreads();
    // E2: softmax over 65 (wave 0)
    if (tid < 64){
      float sz = bo0;
      #pragma unroll
      for (int i = 0; i < 16; ++i) sz += psz[i];
      float zi = zf[tid];
      float m = zi;
      for (int off = 32; off; off >>= 1) m = fmaxf(m, __shfl_xor(m, off, 64));
      m = fmaxf(m, sz);
      float e = __expf(zi - m);
      float s = e;
      for (int off = 32; off; off >>= 1) s += __shfl_xor(s, off, 64);
      float esz = __expf(sz - m);
      float denom = s + esz;
      wL[tid] = e/denom;
      if (tid == 0) wL[64] = esz/denom;
    }
    __syncthreads();
    // F: attended, ctx, new_h
    if (tid < 256){
      float att = 0.f;
      #pragma unroll 4
      for (int n2 = 0; n2 < 64; ++n2) att += VL[n2*256 + tid]*wL[n2];
      float beta = wL[64];
      float ctx = (1.f - beta)*att;
      ctxsum += ctx;
      hL[tid] = beta*sentL[tid] + ctx + hnewL[tid];
    }
    __syncthreads();
  }
  // epilogue: heads
  if (tid < 256) ctxmL[tid] = ctxsum*(1.f/32.f);
  __syncthreads();
  if (tid < 256){
    float a = tob1[tid];
    const float* w = tow1 + (size_t)tid*256;
    #pragma unroll 4
    for (int c = 0; c < 256; ++c) a += hL[c]*w[c];
    tmpL[tid] = a > 0.f ? a : 0.f;
  }
  __syncthreads();
  if (tid < 128){
    float s = sob[tid];
    const float* w = sow + (size_t)tid*256;
    #pragma unroll 4
    for (int c = 0; c < 256; ++c) s += ctxmL[c]*w[c];
    out[b*128 + tid] = s;
    float tx = tob2[tid];
    const float* w2 = tow2 + (size_t)tid*256;
    #pragma unroll 4
    for (int k = 0; k < 256; ++k) tx += tmpL[k]*w2[k];
    out[8192 + b*128 + tid] = tx;
  }
}

extern "C" void kernel_launch(void* const* d_in, const int* in_sizes, int n_in,
                              void* d_out, int out_size, void* d_ws, size_t ws_size,
                              hipStream_t stream){
  const float* shape_in = (const float*)d_in[0];
  const int*   text_in  = (const int*)d_in[1];
  const float* c1w = (const float*)d_in[2];
  const float* c1b = (const float*)d_in[3];
  const float* g1  = (const float*)d_in[4];
  const float* be1 = (const float*)d_in[5];
  const float* c2w = (const float*)d_in[6];
  const float* c2b = (const float*)d_in[7];
  const float* g2  = (const float*)d_in[8];
  const float* be2 = (const float*)d_in[9];
  const float* c3w = (const float*)d_in[10];
  const float* c3b = (const float*)d_in[11];
  const float* g3  = (const float*)d_in[12];
  const float* be3 = (const float*)d_in[13];
  const float* sow = (const float*)d_in[14];
  const float* sob = (const float*)d_in[15];
  const float* emb = (const float*)d_in[16];
  const float* t1w = (const float*)d_in[17];
  const float* t1b = (const float*)d_in[18];
  const float* t2w = (const float*)d_in[19];
  const float* g128= (const float*)d_in[20];
  const float* b128= (const float*)d_in[21];
  const float* t3w = (const float*)d_in[22];
  const float* t3b = (const float*)d_in[23];
  const float* t4w = (const float*)d_in[24];
  const float* g256= (const float*)d_in[25];
  const float* b256= (const float*)d_in[26];
  const float* tow1= (const float*)d_in[27];
  const float* tob1= (const float*)d_in[28];
  const float* tow2= (const float*)d_in[29];
  const float* tob2= (const float*)d_in[30];
  const float* wih = (const float*)d_in[31];
  const float* whh = (const float*)d_in[32];
  const float* bih = (const float*)d_in[33];
  const float* bhh = (const float*)d_in[34];
  const float* wxg = (const float*)d_in[35];
  const float* bxg = (const float*)d_in[36];
  const float* whg = (const float*)d_in[37];
  const float* bhg = (const float*)d_in[38];
  const float* wv  = (const float*)d_in[39];
  const float* bv  = (const float*)d_in[40];
  const float* wh  = (const float*)d_in[41];
  const float* bh  = (const float*)d_in[42];
  const float* wsw = (const float*)d_in[43];
  const float* bsb = (const float*)d_in[44];
  const float* wo  = (const float*)d_in[45];
  const float* bo  = (const float*)d_in[46];
  float* out = (float*)d_out;
  float* Wk = (float*)d_ws;

  if (ws_size < (size_t)24905088*4) return;  // need ~99.6 MB

  float* x1     = Wk + 0;
  float* xih    = Wk + 0;           // reuses x1 region (after conv2)
  float* xg     = Wk + 2097152;
  float* vproj  = Wk + 2621440;
  float* x2     = Wk + 16777216;
  float* Vb     = Wk + 20971520;
  float* tE     = Wk + 22020096;
  float* tA     = Wk + 22282240;
  float* tB     = Wk + 22544384;
  float* tC     = Wk + 22806528;
  float* tD     = Wk + 23330816;
  float* whhT_  = Wk + 23855104;
  float* whgT_  = Wk + 24117248;
  float* whT_   = Wk + 24182784;
  float* wsT_   = Wk + 24313856;
  float* wvT_   = Wk + 24444928;
  float* wihT_  = Wk + 24576000;
  float* wxgT_  = Wk + 24838144;
  float* scale1 = Wk + 24903680;
  float* shift1 = scale1 + 64;
  float* scale2 = shift1 + 64;
  float* shift2 = scale2 + 128;
  float* scale3 = shift2 + 128;
  float* shift3 = scale3 + 256;
  float* sums   = shift3 + 256;     // 512 floats

  // weight transposes
  k_transpose<<<1024,256,0,stream>>>(whhT_, whh, 1024, 256);
  k_transpose<<<256, 256,0,stream>>>(whgT_, whg, 256, 256);
  k_transpose<<<512, 256,0,stream>>>(whT_,  wh,  512, 256);
  k_transpose<<<512, 256,0,stream>>>(wsT_,  wsw, 512, 256);
  k_transpose<<<512, 256,0,stream>>>(wvT_,  wv,  512, 256);
  k_transpose<<<1024,256,0,stream>>>(wihT_, wih, 1024, 256);
  k_transpose<<<256, 256,0,stream>>>(wxgT_, wxg, 256, 256);

  // text branch
  k_embed<<<1024,256,0,stream>>>(tE, emb, text_in);
  k_conv1d<<<dim3(2,64),256,0,stream>>>(tE, t1w, t1b, tA, 128, 128);
  k_conv1d<<<dim3(2,64),256,0,stream>>>(tA, t2w, nullptr, tB, 128, 128);
  k_bn_text<<<128,256,0,stream>>>(tB, g128, b128, 128);
  k_conv1d<<<dim3(4,64),256,0,stream>>>(tB, t3w, t3b, tC, 128, 256);
  k_conv1d<<<dim3(4,64),256,0,stream>>>(tC, t4w, nullptr, tD, 256, 256);
  k_bn_text<<<256,256,0,stream>>>(tD, g256, b256, 256);

  // conv1 + bn1 stats
  k_conv1<<<dim3(16,64,64),256,0,stream>>>(shape_in, c1w, c1b, x1);
  hipMemsetAsync(sums, 0, 2*64*sizeof(float), stream);
  k_bn_partial<<<64*16,256,0,stream>>>(x1, sums, 64, 4096, 16);
  k_bn_finalize<<<1,64,0,stream>>>(sums, g1, be1, scale1, shift1, 64, 4096);

  // conv2 + bn2 stats
  k_conv2<<<dim3(8,16,64),512,0,stream>>>(x1, c2w, c2b, scale1, shift1, x2);
  hipMemsetAsync(sums, 0, 2*128*sizeof(float), stream);
  k_bn_partial<<<128*8,256,0,stream>>>(x2, sums, 128, 512, 8);
  k_bn_finalize<<<2,64,0,stream>>>(sums, g2, be2, scale2, shift2, 128, 512);

  // x-projections (after conv2: reuses x1 region; tD ready)
  k_xproj<<<256,256,0,stream>>>(tD, wihT_, wxgT_, bih, bhh, bxg, bhg, xih, xg);

  // conv3 + bn3 stats + normalize
  k_conv3<<<dim3(32,64),512,0,stream>>>(x2, c3w, c3b, scale2, shift2, Vb);
  hipMemsetAsync(sums, 0, 2*256*sizeof(float), stream);
  k_bn_partial<<<256*2,256,0,stream>>>(Vb, sums, 256, 64, 2);
  k_bn_finalize<<<4,64,0,stream>>>(sums, g3, be3, scale3, shift3, 256, 64);
  k_bn_apply<<<4096,256,0,stream>>>(Vb, scale3, shift3);

  // vproj
  k_vproj<<<dim3(8,64),512,0,stream>>>(Vb, wvT_, bv, vproj);

  // scan + fused heads
  k_scan<<<64,1024,0,stream>>>(Vb, vproj, xih, xg, whhT_, whgT_, whT_, wsT_,
                               bh, bsb, wo, bo, sow, sob, tow1, tob1, tow2, tob2, out);
}

// Round 2
// 2579.502 us; speedup vs baseline: 2.2193x; 2.2193x over previous
//
#include <hip/hip_runtime.h>
#include <math.h>

#define EPSB 1e-5f

__device__ __forceinline__ float fsig(float x){ x = fminf(fmaxf(x,-30.f),30.f); return 1.f/(1.f+__expf(-x)); }
__device__ __forceinline__ float ftanh(float x){ x = fminf(fmaxf(x,-15.f),15.f); float t = __expf(2.f*x); return (t-1.f)/(t+1.f); }

// ---------------- transpose: dst[c*R+r] = src[r*C+c] ----------------
__global__ __launch_bounds__(256) void k_transpose(float* __restrict__ dst, const float* __restrict__ src, int R, int C){
  int t = blockIdx.x*256 + threadIdx.x;
  if (t >= R*C) return;
  int r = t / C, c = t - r*C;
  dst[c*R + r] = src[t];
}

// ---------------- embedding: tE[b][ch][l] = emb[idx[b][l]][ch] ----------------
__global__ __launch_bounds__(256) void k_embed(float* __restrict__ tE, const float* __restrict__ emb, const int* __restrict__ idx){
  int t = blockIdx.x*256 + threadIdx.x;   // < 64*128*32
  int b = t >> 12, r = t & 4095, ch = r >> 5, l = r & 31;
  tE[t] = emb[idx[b*32 + l]*128 + ch];
}

// ---------------- text conv1d (k=3, pad=1) + relu ----------------
__global__ __launch_bounds__(256) void k_conv1d(const float* __restrict__ in, const float* __restrict__ w,
    const float* __restrict__ bias, float* __restrict__ out, int Cin, int Cout){
  __shared__ float inL[8192];
  int b = blockIdx.y, tid = threadIdx.x;
  int n = Cin*32;
  for (int i = tid; i < n; i += 256) inL[i] = in[(size_t)b*n + i];
  __syncthreads();
  int u = blockIdx.x*256 + tid;     // < Cout*4
  int co = u >> 2, l0 = (u & 3)*8;
  float acc[8];
  #pragma unroll
  for (int l = 0; l < 8; ++l) acc[l] = 0.f;
  for (int ci = 0; ci < Cin; ++ci){
    float rin[10];
    #pragma unroll
    for (int ii = 0; ii < 10; ++ii){
      int p = l0 - 1 + ii;
      rin[ii] = (p >= 0 && p < 32) ? inL[ci*32 + p] : 0.f;
    }
    const float* wp = w + ((size_t)co*Cin + ci)*3;
    float w0 = wp[0], w1 = wp[1], w2 = wp[2];
    #pragma unroll
    for (int l = 0; l < 8; ++l) acc[l] += rin[l]*w0 + rin[l+1]*w1 + rin[l+2]*w2;
  }
  float bb = bias ? bias[co] : 0.f;
  #pragma unroll
  for (int l = 0; l < 8; ++l){
    float v = acc[l] + bb;
    out[((size_t)b*Cout + co)*32 + l0 + l] = v > 0.f ? v : 0.f;
  }
}

// ---------------- text bn (per-channel over B*L=2048), in place ----------------
__global__ __launch_bounds__(256) void k_bn_text(float* __restrict__ x, const float* __restrict__ g, const float* __restrict__ be, int C){
  __shared__ float s1[256], s2[256];
  __shared__ float sc[2];
  int c = blockIdx.x, tid = threadIdx.x;
  float sum = 0.f, ss = 0.f;
  for (int i = tid; i < 2048; i += 256){
    int b = i >> 5, l = i & 31;
    float v = x[((size_t)b*C + c)*32 + l];
    sum += v; ss += v*v;
  }
  s1[tid] = sum; s2[tid] = ss;
  __syncthreads();
  for (int off = 128; off; off >>= 1){
    if (tid < off){ s1[tid] += s1[tid+off]; s2[tid] += s2[tid+off]; }
    __syncthreads();
  }
  if (tid == 0){
    float mean = s1[0]*(1.f/2048.f);
    float var  = s2[0]*(1.f/2048.f) - mean*mean;
    float rs = rsqrtf(var + EPSB);
    sc[0] = g[c]*rs;
    sc[1] = be[c] - mean*g[c]*rs;
  }
  __syncthreads();
  float a = sc[0], bsh = sc[1];
  for (int i = tid; i < 2048; i += 256){
    int b = i >> 5, l = i & 31;
    size_t o = ((size_t)b*C + c)*32 + l;
    x[o] = x[o]*a + bsh;
  }
}

// ---------------- conv bn: partial sums (atomic) + finalize ----------------
__global__ __launch_bounds__(256) void k_bn_partial(const float* __restrict__ x, float* __restrict__ sums, int C, int S, int split){
  __shared__ float s1[256], s2[256];
  int c = blockIdx.x / split, chunk = blockIdx.x - c*split;
  int tid = threadIdx.x;
  int n = 64*S, per = n/split, i0 = chunk*per;
  float sum = 0.f, ss = 0.f;
  for (int i = i0 + tid; i < i0 + per; i += 256){
    int b = i / S, s = i - b*S;
    float v = x[((size_t)b*C + c)*S + s];
    sum += v; ss += v*v;
  }
  s1[tid] = sum; s2[tid] = ss;
  __syncthreads();
  for (int off = 128; off; off >>= 1){
    if (tid < off){ s1[tid] += s1[tid+off]; s2[tid] += s2[tid+off]; }
    __syncthreads();
  }
  if (tid == 0){
    atomicAdd(&sums[c], s1[0]);
    atomicAdd(&sums[C + c], s2[0]);
  }
}

__global__ void k_bn_finalize(const float* __restrict__ sums, const float* __restrict__ g, const float* __restrict__ be,
    float* __restrict__ scale, float* __restrict__ shift, int C, int S){
  int c = blockIdx.x*64 + threadIdx.x;
  if (c >= C) return;
  float n = 64.f*(float)S;
  float mean = sums[c]/n;
  float var  = sums[C+c]/n - mean*mean;
  float rs = rsqrtf(var + EPSB);
  scale[c] = g[c]*rs;
  shift[c] = be[c] - mean*g[c]*rs;
}

// ---------------- conv1: (64,4,32^3) -> (64,64,16^3), stride2 pad1 k3, relu ----------------
// parity-deinterleaved LDS tile, 4co x 4x register tile per thread.
// tile row: [even ix/2: 0..15][odd (ix+1)/2: 16..32][pad:33..35], row stride 36
__global__ __launch_bounds__(256) void k_conv1(const float* __restrict__ in, const float* __restrict__ wT1,
    const float* __restrict__ bias, float* __restrict__ out){
  __shared__ float tile[3888];  // 4ci * 3dz * 9iy * 36
  int z = blockIdx.x, yq = blockIdx.y, b = blockIdx.z, tid = threadIdx.x;
  int cog = tid & 15, posg = tid >> 4;
  int yy = posg >> 2, xq = posg & 3;
  // fill (dest-indexed; invalid -> 0)
  for (int i = tid; i < 3564; i += 256){
    int r = i/33, col = i - r*33;
    int ci = r/27, rr = r - 27*ci, dz = rr/9, iyl = rr - 9*dz;
    int iz = 2*z - 1 + dz;
    int iy = 8*yq - 1 + iyl;
    int ix = (col < 16) ? 2*col : 2*(col-16)-1;
    float v = 0.f;
    if (iz >= 0 && iz < 32 && iy >= 0 && ix >= 0)
      v = in[(((size_t)b*4 + ci)*32 + iz)*1024 + iy*32 + ix];
    tile[r*36 + col] = v;
  }
  __syncthreads();
  float acc[4][4];
  #pragma unroll
  for (int c = 0; c < 4; ++c){
    #pragma unroll
    for (int x = 0; x < 4; ++x) acc[c][x] = 0.f;
  }
  #pragma unroll 1
  for (int ci = 0; ci < 4; ++ci){
    #pragma unroll
    for (int dz = 0; dz < 3; ++dz){
      #pragma unroll
      for (int dy = 0; dy < 3; ++dy){
        int row = ci*972 + dz*324 + (2*yy + dy)*36;
        float4 ev = *(const float4*)&tile[row + 4*xq];
        float4 od = *(const float4*)&tile[row + 16 + 4*xq];
        float od4 = tile[row + 20 + 4*xq];
        const float* wp = wT1 + (ci*27 + dz*9 + dy*3)*64 + 4*cog;
        float4 w0 = *(const float4*)(wp);
        float4 w1 = *(const float4*)(wp + 64);
        float4 w2 = *(const float4*)(wp + 128);
        float iv0[4] = {od.x, od.y, od.z, od.w};
        float iv1[4] = {ev.x, ev.y, ev.z, ev.w};
        float iv2[4] = {od.y, od.z, od.w, od4};
        float wa0[4] = {w0.x,w0.y,w0.z,w0.w};
        float wa1[4] = {w1.x,w1.y,w1.z,w1.w};
        float wa2[4] = {w2.x,w2.y,w2.z,w2.w};
        #pragma unroll
        for (int c = 0; c < 4; ++c){
          #pragma unroll
          for (int x = 0; x < 4; ++x)
            acc[c][x] += wa0[c]*iv0[x] + wa1[c]*iv1[x] + wa2[c]*iv2[x];
        }
      }
    }
  }
  float4 bi = *(const float4*)&bias[4*cog];
  float ba[4] = {bi.x,bi.y,bi.z,bi.w};
  int y = yq*4 + yy;
  #pragma unroll
  for (int c = 0; c < 4; ++c){
    int co = 4*cog + c;
    float4 o;
    float* op = (float*)&o;
    #pragma unroll
    for (int x = 0; x < 4; ++x){
      float v = acc[c][x] + ba[c];
      op[x] = v > 0.f ? v : 0.f;
    }
    *(float4*)&out[(((size_t)b*64 + co)*16 + z)*256 + y*16 + 4*xq] = o;
  }
}

// ---------------- conv2: (64,64,16^3)->(64,128,8^3); bn1 affine on load ----------------
// tile row: [even 0..7][odd 8..16][pad 17..19], stride 20; ci-chunk 16
__global__ __launch_bounds__(256) void k_conv2(const float* __restrict__ x1, const float* __restrict__ wT2,
    const float* __restrict__ bias, const float* __restrict__ scale, const float* __restrict__ shift,
    float* __restrict__ out){
  __shared__ float tile[16320];   // 16ci * 3dz * 17iy * 20
  __shared__ float sclL[64], shfL[64];
  int z = blockIdx.x, coh = blockIdx.y, b = blockIdx.z, tid = threadIdx.x;
  int cog = tid & 15, posg = tid >> 4;
  int y = posg >> 1, xq = posg & 1;
  if (tid < 64){ sclL[tid] = scale[tid]; shfL[tid] = shift[tid]; }
  float acc[4][4];
  #pragma unroll
  for (int c = 0; c < 4; ++c){
    #pragma unroll
    for (int x = 0; x < 4; ++x) acc[c][x] = 0.f;
  }
  for (int ci0 = 0; ci0 < 64; ci0 += 16){
    __syncthreads();
    for (int i = tid; i < 13872; i += 256){
      int q = i/289, rem = i - q*289;
      int iyr = rem/17, col = rem - iyr*17;
      int ci = q/3, dz = q - 3*ci;
      int iz = 2*z - 1 + dz;
      int iy = iyr - 1;
      int ix = (col < 8) ? 2*col : 2*(col-8)-1;
      int cc = ci0 + ci;
      float v = 0.f;
      if (iz >= 0 && iz < 16 && iy >= 0 && ix >= 0)
        v = x1[(((size_t)b*64 + cc)*16 + iz)*256 + iy*16 + ix]*sclL[cc] + shfL[cc];
      tile[q*340 + iyr*20 + col] = v;
    }
    __syncthreads();
    #pragma unroll 1
    for (int ci = 0; ci < 16; ++ci){
      const float* wp = wT2 + ((size_t)(ci0+ci)*27)*128 + coh*64 + 4*cog;
      #pragma unroll
      for (int dz = 0; dz < 3; ++dz){
        #pragma unroll
        for (int dy = 0; dy < 3; ++dy){
          int row = ci*1020 + dz*340 + (2*y + dy)*20;
          float4 ev = *(const float4*)&tile[row + 4*xq];
          float4 od = *(const float4*)&tile[row + 8 + 4*xq];
          float od4 = tile[row + 12 + 4*xq];
          const float* wq = wp + (dz*9 + dy*3)*128;
          float4 w0 = *(const float4*)(wq);
          float4 w1 = *(const float4*)(wq + 128);
          float4 w2 = *(const float4*)(wq + 256);
          float iv0[4] = {od.x, od.y, od.z, od.w};
          float iv1[4] = {ev.x, ev.y, ev.z, ev.w};
          float iv2[4] = {od.y, od.z, od.w, od4};
          float wa0[4] = {w0.x,w0.y,w0.z,w0.w};
          float wa1[4] = {w1.x,w1.y,w1.z,w1.w};
          float wa2[4] = {w2.x,w2.y,w2.z,w2.w};
          #pragma unroll
          for (int c = 0; c < 4; ++c){
            #pragma unroll
            for (int x = 0; x < 4; ++x)
              acc[c][x] += wa0[c]*iv0[x] + wa1[c]*iv1[x] + wa2[c]*iv2[x];
          }
        }
      }
    }
  }
  float4 bi = *(const float4*)&bias[coh*64 + 4*cog];
  float ba[4] = {bi.x,bi.y,bi.z,bi.w};
  #pragma unroll
  for (int c = 0; c < 4; ++c){
    int co = coh*64 + 4*cog + c;
    float4 o;
    float* op = (float*)&o;
    #pragma unroll
    for (int x = 0; x < 4; ++x){
      float v = acc[c][x] + ba[c];
      op[x] = v > 0.f ? v : 0.f;
    }
    *(float4*)&out[(((size_t)b*128 + co)*8 + z)*64 + y*8 + 4*xq] = o;
  }
}

// ---------------- conv3: (64,128,8^3)->(64,256,4^3); bn2 affine on load ----------------
// tile row: [even 0..3][odd 4..8][pad 9..11], stride 12; full 3D (9iz x 9iy); ci-chunk 16
__global__ __launch_bounds__(512) void k_conv3(const float* __restrict__ x2, const float* __restrict__ wT3,
    const float* __restrict__ bias, const float* __restrict__ scale, const float* __restrict__ shift,
    float* __restrict__ out){
  __shared__ float tile[15552];   // 16ci * 9iz * 9iy * 12
  __shared__ float sclL[128], shfL[128];
  int coq = blockIdx.x, b = blockIdx.y, tid = threadIdx.x;
  int cog = tid & 15, posg = tid >> 4;      // 0..31
  int zz = posg >> 3, y = (posg >> 1) & 3, xh = posg & 1;
  if (tid < 128){ sclL[tid] = scale[tid]; shfL[tid] = shift[tid]; }
  float acc[4][2];
  #pragma unroll
  for (int c = 0; c < 4; ++c){ acc[c][0] = 0.f; acc[c][1] = 0.f; }
  for (int ci0 = 0; ci0 < 128; ci0 += 16){
    __syncthreads();
    for (int i = tid; i < 11664; i += 512){
      int ci = i/729, rem = i - ci*729;
      int izr = rem/81, rem2 = rem - izr*81;
      int iyr = rem2/9, col = rem2 - iyr*9;
      int iz = izr - 1, iy = iyr - 1;
      int ix = (col < 4) ? 2*col : 2*(col-4)-1;
      int cc = ci0 + ci;
      float v = 0.f;
      if (iz >= 0 && iy >= 0 && ix >= 0)
        v = x2[((size_t)b*128 + cc)*512 + iz*64 + iy*8 + ix]*sclL[cc] + shfL[cc];
      tile[ci*972 + izr*108 + iyr*12 + col] = v;
    }
    __syncthreads();
    #pragma unroll 1
    for (int ci = 0; ci < 16; ++ci){
      const float* wp = wT3 + ((size_t)(ci0+ci)*27)*256 + coq*64 + 4*cog;
      #pragma unroll
      for (int dz = 0; dz < 3; ++dz){
        #pragma unroll
        for (int dy = 0; dy < 3; ++dy){
          int row = ci*972 + (2*zz + dz)*108 + (2*y + dy)*12;
          float2 ev = *(const float2*)&tile[row + 2*xh];
          float2 od = *(const float2*)&tile[row + 4 + 2*xh];
          float od1 = tile[row + 6 + 2*xh];
          const float* wq = wp + (dz*9 + dy*3)*256;
          float4 w0 = *(const float4*)(wq);
          float4 w1 = *(const float4*)(wq + 256);
          float4 w2 = *(const float4*)(wq + 512);
          float iv0[2] = {od.x, od.y};
          float iv1[2] = {ev.x, ev.y};
          float iv2[2] = {od.y, od1};
          float wa0[4] = {w0.x,w0.y,w0.z,w0.w};
          float wa1[4] = {w1.x,w1.y,w1.z,w1.w};
          float wa2[4] = {w2.x,w2.y,w2.z,w2.w};
          #pragma unroll
          for (int c = 0; c < 4; ++c){
            #pragma unroll
            for (int x = 0; x < 2; ++x)
              acc[c][x] += wa0[c]*iv0[x] + wa1[c]*iv1[x] + wa2[c]*iv2[x];
          }
        }
      }
    }
  }
  float4 bi = *(const float4*)&bias[coq*64 + 4*cog];
  float ba[4] = {bi.x,bi.y,bi.z,bi.w};
  #pragma unroll
  for (int c = 0; c < 4; ++c){
    int co = coq*64 + 4*cog + c;
    float2 o;
    float v0 = acc[c][0] + ba[c], v1 = acc[c][1] + ba[c];
    o.x = v0 > 0.f ? v0 : 0.f;
    o.y = v1 > 0.f ? v1 : 0.f;
    *(float2*)&out[((size_t)b*256 + co)*64 + zz*16 + y*4 + 2*xh] = o;
  }
}

// ---------------- bn3 apply in place on V (64,256,64) ----------------
__global__ __launch_bounds__(256) void k_bn_apply(float* __restrict__ x, const float* __restrict__ scale, const float* __restrict__ shift){
  int i = blockIdx.x*256 + threadIdx.x;
  int c = (i >> 6) & 255;
  x[i] = x[i]*scale[c] + shift[c];
}

// ---------------- x-projections ----------------
__global__ __launch_bounds__(256) void k_xproj(const float* __restrict__ tD,
    const float* __restrict__ wihT, const float* __restrict__ wxgT,
    const float* __restrict__ bih, const float* __restrict__ bhh,
    const float* __restrict__ bxg, const float* __restrict__ bhg,
    float* __restrict__ xih, float* __restrict__ xg){
  __shared__ float xr[8][256];
  int b = blockIdx.x >> 2, t0 = (blockIdx.x & 3)*8, tid = threadIdx.x;
  for (int i = tid; i < 2048; i += 256){
    int tt = i >> 8, c = i & 255;
    xr[tt][c] = tD[((size_t)b*256 + c)*32 + t0 + tt];
  }
  __syncthreads();
  float4 bi = ((const float4*)bih)[tid];
  float4 b2 = ((const float4*)bhh)[tid];
  float4 binit = make_float4(bi.x+b2.x, bi.y+b2.y, bi.z+b2.z, bi.w+b2.w);
  float4 a[8];
  #pragma unroll
  for (int tt = 0; tt < 8; ++tt) a[tt] = binit;
  const float4* Wq = (const float4*)wihT;
  for (int k = 0; k < 256; ++k){
    float4 w = Wq[k*256 + tid];
    #pragma unroll
    for (int tt = 0; tt < 8; ++tt){
      float xv = xr[tt][k];
      a[tt].x += xv*w.x; a[tt].y += xv*w.y; a[tt].z += xv*w.z; a[tt].w += xv*w.w;
    }
  }
  #pragma unroll
  for (int tt = 0; tt < 8; ++tt)
    ((float4*)xih)[((size_t)(b*32 + t0 + tt))*256 + tid] = a[tt];
  if (tid < 64){
    float4 bg = ((const float4*)bxg)[tid];
    float4 bg2 = ((const float4*)bhg)[tid];
    float4 ginit = make_float4(bg.x+bg2.x, bg.y+bg2.y, bg.z+bg2.z, bg.w+bg2.w);
    float4 g[8];
    #pragma unroll
    for (int tt = 0; tt < 8; ++tt) g[tt] = ginit;
    const float4* Wg = (const float4*)wxgT;
    for (int k = 0; k < 256; ++k){
      float4 w = Wg[k*64 + tid];
      #pragma unroll
      for (int tt = 0; tt < 8; ++tt){
        float xv = xr[tt][k];
        g[tt].x += xv*w.x; g[tt].y += xv*w.y; g[tt].z += xv*w.z; g[tt].w += xv*w.w;
      }
    }
    #pragma unroll
    for (int tt = 0; tt < 8; ++tt)
      ((float4*)xg)[((size_t)(b*32 + t0 + tt))*64 + tid] = g[tt];
  }
}

// ---------------- vproj[b][n][o] = sum_c V[b][c][n]*wvT[c][o] + bv[o] ----------------
__global__ __launch_bounds__(512) void k_vproj(const float* __restrict__ V, const float* __restrict__ wvT,
    const float* __restrict__ bv, float* __restrict__ vproj){
  __shared__ float Vc[8][256];
  int n0 = blockIdx.x*8, b = blockIdx.y, tid = threadIdx.x;
  for (int i = tid; i < 2048; i += 512){
    int nn = i >> 8, c = i & 255;
    Vc[nn][c] = V[((size_t)b*256 + c)*64 + n0 + nn];
  }
  __syncthreads();
  float acc[8];
  float bb = bv[tid];
  #pragma unroll
  for (int nn = 0; nn < 8; ++nn) acc[nn] = bb;
  for (int k = 0; k < 256; ++k){
    float w = wvT[k*512 + tid];
    #pragma unroll
    for (int nn = 0; nn < 8; ++nn) acc[nn] += Vc[nn][k]*w;
  }
  #pragma unroll
  for (int nn = 0; nn < 8; ++nn)
    vproj[((size_t)(b*64 + n0 + nn))*512 + tid] = acc[nn];
}

// ---------------- the recurrent attention scan: one workgroup per batch row ----------------
__global__ __launch_bounds__(1024) void k_scan(
    const float* __restrict__ V,
    const float* __restrict__ vproj,
    const float* __restrict__ xih,
    const float* __restrict__ xg,
    const float* __restrict__ whhT,
    const float* __restrict__ whgT,
    const float* __restrict__ whT,
    const float* __restrict__ wsT,
    const float* __restrict__ bh,
    const float* __restrict__ bs,
    const float* __restrict__ wo,
    const float* __restrict__ bo,
    const float* __restrict__ sow, const float* __restrict__ sob,
    const float* __restrict__ tow1, const float* __restrict__ tob1,
    const float* __restrict__ tow2, const float* __restrict__ tob2,
    float* __restrict__ out)
{
  __shared__ float VL[16384];                 // [n][c]
  __shared__ __align__(16) float gatesL[1024];
  __shared__ __align__(16) float hgL[256];
  __shared__ float hL[256], hnewL[256], sentL[256];
  __shared__ __align__(16) float hpL[512], spL[512];
  __shared__ float red[1536];
  __shared__ float zf[64], psz[16], wL[65];
  __shared__ float woL[512];
  __shared__ float ctxmL[256], tmpL[256];

  int b = blockIdx.x, tid = threadIdx.x;
  for (int i = tid; i < 16384; i += 1024){
    int c = i >> 6, n2 = i & 63;
    VL[n2*256 + c] = V[((size_t)b*256 + c)*64 + n2];
  }
  if (tid < 512) woL[tid] = wo[tid];
  if (tid < 256) hL[tid] = 0.f;
  float creg = 0.f, ctxsum = 0.f;
  float bo0 = bo[0];
  __syncthreads();

  for (int t = 0; t < 32; ++t){
    if (tid < 256){
      float4 acc = ((const float4*)(xih + ((size_t)(b*32 + t))*1024))[tid];
      const float4* Wq = (const float4*)whhT;
      #pragma unroll 4
      for (int k = 0; k < 256; ++k){
        float hk = hL[k];
        float4 w = Wq[k*256 + tid];
        acc.x += hk*w.x; acc.y += hk*w.y; acc.z += hk*w.z; acc.w += hk*w.w;
      }
      ((float4*)gatesL)[tid] = acc;
    } else if (tid < 320){
      int j = tid - 256;
      float4 acc = ((const float4*)(xg + ((size_t)(b*32 + t))*256))[j];
      const float4* Wq = (const float4*)whgT;
      #pragma unroll 4
      for (int k = 0; k < 256; ++k){
        float hk = hL[k];
        float4 w = Wq[k*64 + j];
        acc.x += hk*w.x; acc.y += hk*w.y; acc.z += hk*w.z; acc.w += hk*w.w;
      }
      ((float4*)hgL)[j] = acc;
    }
    __syncthreads();
    if (tid < 256){
      float i_ = fsig(gatesL[tid]);
      float f_ = fsig(gatesL[256 + tid]);
      float g_ = ftanh(gatesL[512 + tid]);
      float o_ = fsig(gatesL[768 + tid]);
      float cn = f_*creg + i_*g_;
      creg = cn;
      float tc = ftanh(cn);
      hnewL[tid] = o_*tc;
      sentL[tid] = fsig(hgL[tid])*tc;
    }
    __syncthreads();
    if (tid < 128){
      float4 acc = ((const float4*)bh)[tid];
      const float4* Wq = (const float4*)whT;
      #pragma unroll 4
      for (int k = 0; k < 256; ++k){
        float hk = hnewL[k];
        float4 w = Wq[k*128 + tid];
        acc.x += hk*w.x; acc.y += hk*w.y; acc.z += hk*w.z; acc.w += hk*w.w;
      }
      ((float4*)hpL)[tid] = acc;
    } else if (tid < 256){
      int j = tid - 128;
      float4 acc = ((const float4*)bs)[j];
      const float4* Wq = (const float4*)wsT;
      #pragma unroll 4
      for (int k = 0; k < 256; ++k){
        float sk = sentL[k];
        float4 w = Wq[k*128 + j];
        acc.x += sk*w.x; acc.y += sk*w.y; acc.z += sk*w.z; acc.w += sk*w.w;
      }
      ((float4*)spL)[j] = acc;
    }
    __syncthreads();
    {
      int n2 = tid >> 4, seg = tid & 15;
      const float* vp = vproj + ((size_t)(b*64 + n2))*512 + seg*32;
      float a = 0.f;
      #pragma unroll 4
      for (int o = 0; o < 32; ++o){
        int oo = seg*32 + o;
        a += ftanh(vp[o] + hpL[oo])*woL[oo];
      }
      red[tid] = a;
    }
    if (tid < 512)
      red[1024 + tid] = ftanh(spL[tid] + hpL[tid])*woL[tid];
    __syncthreads();
    if (tid < 64){
      float s = 0.f;
      #pragma unroll
      for (int i = 0; i < 16; ++i) s += red[tid*16 + i];
      zf[tid] = s + bo0;
    } else if (tid < 80){
      float s = 0.f;
      #pragma unroll
      for (int i = 0; i < 32; ++i) s += red[1024 + (tid-64)*32 + i];
      psz[tid - 64] = s;
    }
    __syncthreads();
    if (tid < 64){
      float sz = bo0;
      #pragma unroll
      for (int i = 0; i < 16; ++i) sz += psz[i];
      float zi = zf[tid];
      float m = zi;
      for (int off = 32; off; off >>= 1) m = fmaxf(m, __shfl_xor(m, off, 64));
      m = fmaxf(m, sz);
      float e = __expf(zi - m);
      float s = e;
      for (int off = 32; off; off >>= 1) s += __shfl_xor(s, off, 64);
      float esz = __expf(sz - m);
      float denom = s + esz;
      wL[tid] = e/denom;
      if (tid == 0) wL[64] = esz/denom;
    }
    __syncthreads();
    if (tid < 256){
      float att = 0.f;
      #pragma unroll 4
      for (int n2 = 0; n2 < 64; ++n2) att += VL[n2*256 + tid]*wL[n2];
      float beta = wL[64];
      float ctx = (1.f - beta)*att;
      ctxsum += ctx;
      hL[tid] = beta*sentL[tid] + ctx + hnewL[tid];
    }
    __syncthreads();
  }
  if (tid < 256) ctxmL[tid] = ctxsum*(1.f/32.f);
  __syncthreads();
  if (tid < 256){
    float a = tob1[tid];
    const float* w = tow1 + (size_t)tid*256;
    #pragma unroll 4
    for (int c = 0; c < 256; ++c) a += hL[c]*w[c];
    tmpL[tid] = a > 0.f ? a : 0.f;
  }
  __syncthreads();
  if (tid < 128){
    float s = sob[tid];
    const float* w = sow + (size_t)tid*256;
    #pragma unroll 4
    for (int c = 0; c < 256; ++c) s += ctxmL[c]*w[c];
    out[b*128 + tid] = s;
    float tx = tob2[tid];
    const float* w2 = tow2 + (size_t)tid*256;
    #pragma unroll 4
    for (int k = 0; k < 256; ++k) tx += tmpL[k]*w2[k];
    out[8192 + b*128 + tid] = tx;
  }
}

extern "C" void kernel_launch(void* const* d_in, const int* in_sizes, int n_in,
                              void* d_out, int out_size, void* d_ws, size_t ws_size,
                              hipStream_t stream){
  const float* shape_in = (const float*)d_in[0];
  const int*   text_in  = (const int*)d_in[1];
  const float* c1w = (const float*)d_in[2];
  const float* c1b = (const float*)d_in[3];
  const float* g1  = (const float*)d_in[4];
  const float* be1 = (const float*)d_in[5];
  const float* c2w = (const float*)d_in[6];
  const float* c2b = (const float*)d_in[7];
  const float* g2  = (const float*)d_in[8];
  const float* be2 = (const float*)d_in[9];
  const float* c3w = (const float*)d_in[10];
  const float* c3b = (const float*)d_in[11];
  const float* g3  = (const float*)d_in[12];
  const float* be3 = (const float*)d_in[13];
  const float* sow = (const float*)d_in[14];
  const float* sob = (const float*)d_in[15];
  const float* emb = (const float*)d_in[16];
  const float* t1w = (const float*)d_in[17];
  const float* t1b = (const float*)d_in[18];
  const float* t2w = (const float*)d_in[19];
  const float* g128= (const float*)d_in[20];
  const float* b128= (const float*)d_in[21];
  const float* t3w = (const float*)d_in[22];
  const float* t3b = (const float*)d_in[23];
  const float* t4w = (const float*)d_in[24];
  const float* g256= (const float*)d_in[25];
  const float* b256= (const float*)d_in[26];
  const float* tow1= (const float*)d_in[27];
  const float* tob1= (const float*)d_in[28];
  const float* tow2= (const float*)d_in[29];
  const float* tob2= (const float*)d_in[30];
  const float* wih = (const float*)d_in[31];
  const float* whh = (const float*)d_in[32];
  const float* bih = (const float*)d_in[33];
  const float* bhh = (const float*)d_in[34];
  const float* wxg = (const float*)d_in[35];
  const float* bxg = (const float*)d_in[36];
  const float* whg = (const float*)d_in[37];
  const float* bhg = (const float*)d_in[38];
  const float* wv  = (const float*)d_in[39];
  const float* bv  = (const float*)d_in[40];
  const float* wh  = (const float*)d_in[41];
  const float* bh  = (const float*)d_in[42];
  const float* wsw = (const float*)d_in[43];
  const float* bsb = (const float*)d_in[44];
  const float* wo  = (const float*)d_in[45];
  const float* bo  = (const float*)d_in[46];
  float* out = (float*)d_out;
  float* Wk = (float*)d_ws;

  if (ws_size < (size_t)24905088*4) return;  // need ~99.6 MB (unchanged)

  float* x1     = Wk + 0;           // 64*64*4096 (dead after conv2)
  float* xih    = Wk + 0;           // reuses x1 region (after conv2)
  float* xg     = Wk + 2097152;
  float* vproj  = Wk + 2621440;
  float* wT3_   = Wk + 4718592;     // 884736 fl; written after conv2 (x1 dead)
  float* x2     = Wk + 16777216;    // 64*128*512
  float* wT1_   = Wk + 16777216;    // 6912 fl; dead before conv2 writes x2
  float* Vb     = Wk + 20971520;    // 64*256*64
  float* wT2_   = Wk + 20971520;    // 221184 fl; dead before conv3 writes Vb
  float* tE     = Wk + 22020096;
  float* tA     = Wk + 22282240;
  float* tB     = Wk + 22544384;
  float* tC     = Wk + 22806528;
  float* tD     = Wk + 23330816;
  float* whhT_  = Wk + 23855104;
  float* whgT_  = Wk + 24117248;
  float* whT_   = Wk + 24182784;
  float* wsT_   = Wk + 24313856;
  float* wvT_   = Wk + 24444928;
  float* wihT_  = Wk + 24576000;
  float* wxgT_  = Wk + 24838144;
  float* scale1 = Wk + 24903680;
  float* shift1 = scale1 + 64;
  float* scale2 = shift1 + 64;
  float* shift2 = scale2 + 128;
  float* scale3 = shift2 + 128;
  float* shift3 = scale3 + 256;
  float* sums   = shift3 + 256;     // 512 floats

  // weight transposes (scan weights + conv1/conv2 weight layouts)
  k_transpose<<<1024,256,0,stream>>>(whhT_, whh, 1024, 256);
  k_transpose<<<256, 256,0,stream>>>(whgT_, whg, 256, 256);
  k_transpose<<<512, 256,0,stream>>>(whT_,  wh,  512, 256);
  k_transpose<<<512, 256,0,stream>>>(wsT_,  wsw, 512, 256);
  k_transpose<<<512, 256,0,stream>>>(wvT_,  wv,  512, 256);
  k_transpose<<<1024,256,0,stream>>>(wihT_, wih, 1024, 256);
  k_transpose<<<256, 256,0,stream>>>(wxgT_, wxg, 256, 256);
  k_transpose<<<27,  256,0,stream>>>(wT1_,  c1w, 64, 108);
  k_transpose<<<864, 256,0,stream>>>(wT2_,  c2w, 128, 1728);

  // text branch
  k_embed<<<1024,256,0,stream>>>(tE, emb, text_in);
  k_conv1d<<<dim3(2,64),256,0,stream>>>(tE, t1w, t1b, tA, 128, 128);
  k_conv1d<<<dim3(2,64),256,0,stream>>>(tA, t2w, nullptr, tB, 128, 128);
  k_bn_text<<<128,256,0,stream>>>(tB, g128, b128, 128);
  k_conv1d<<<dim3(4,64),256,0,stream>>>(tB, t3w, t3b, tC, 128, 256);
  k_conv1d<<<dim3(4,64),256,0,stream>>>(tC, t4w, nullptr, tD, 256, 256);
  k_bn_text<<<256,256,0,stream>>>(tD, g256, b256, 256);

  // conv1 + bn1 stats
  k_conv1<<<dim3(16,4,64),256,0,stream>>>(shape_in, wT1_, c1b, x1);
  hipMemsetAsync(sums, 0, 2*64*sizeof(float), stream);
  k_bn_partial<<<64*16,256,0,stream>>>(x1, sums, 64, 4096, 16);
  k_bn_finalize<<<1,64,0,stream>>>(sums, g1, be1, scale1, shift1, 64, 4096);

  // conv2 + bn2 stats
  k_conv2<<<dim3(8,2,64),256,0,stream>>>(x1, wT2_, c2b, scale1, shift1, x2);
  hipMemsetAsync(sums, 0, 2*128*sizeof(float), stream);
  k_bn_partial<<<128*8,256,0,stream>>>(x2, sums, 128, 512, 8);
  k_bn_finalize<<<2,64,0,stream>>>(sums, g2, be2, scale2, shift2, 128, 512);

  // x-projections (x1 region now dead -> xih/xg)
  k_xproj<<<256,256,0,stream>>>(tD, wihT_, wxgT_, bih, bhh, bxg, bhg, xih, xg);

  // conv3 weight layout (into dead x1 region), then conv3 + bn3
  k_transpose<<<3456,256,0,stream>>>(wT3_, c3w, 256, 3456);
  k_conv3<<<dim3(4,64),512,0,stream>>>(x2, wT3_, c3b, scale2, shift2, Vb);
  hipMemsetAsync(sums, 0, 2*256*sizeof(float), stream);
  k_bn_partial<<<256*2,256,0,stream>>>(Vb, sums, 256, 64, 2);
  k_bn_finalize<<<4,64,0,stream>>>(sums, g3, be3, scale3, shift3, 256, 64);
  k_bn_apply<<<4096,256,0,stream>>>(Vb, scale3, shift3);

  // vproj
  k_vproj<<<dim3(8,64),512,0,stream>>>(Vb, wvT_, bv, vproj);

  // scan + fused heads
  k_scan<<<64,1024,0,stream>>>(Vb, vproj, xih, xg, whhT_, whgT_, whT_, wsT_,
                               bh, bsb, wo, bo, sow, sob, tow1, tob1, tow2, tob2, out);
}

// Round 3
// 2423.156 us; speedup vs baseline: 2.3625x; 1.0645x over previous
//
#include <hip/hip_runtime.h>
#include <hip/hip_fp16.h>
#include <math.h>

#define EPSB 1e-5f

__device__ __forceinline__ float fsig(float x){ x = fminf(fmaxf(x,-30.f),30.f); return 1.f/(1.f+__expf(-x)); }
__device__ __forceinline__ float ftanh(float x){ x = fminf(fmaxf(x,-15.f),15.f); float t = __expf(2.f*x); return __fdividef(t-1.f, t+1.f); }

typedef _Float16 h2_t __attribute__((ext_vector_type(2)));
__device__ __forceinline__ h2_t as_h2(unsigned u){ union{unsigned x; h2_t h;} c; c.x=u; return c.h; }
__device__ __forceinline__ float dot2f(unsigned w, unsigned h, float acc){
#if __has_builtin(__builtin_amdgcn_fdot2)
  return __builtin_amdgcn_fdot2(as_h2(w), as_h2(h), acc, false);
#else
  __half2 hw = *(__half2*)&w, hh = *(__half2*)&h;
  return acc + __low2float(hw)*__low2float(hh) + __high2float(hw)*__high2float(hh);
#endif
}

// ---------------- transpose: dst[c*R+r] = src[r*C+c] ----------------
__global__ __launch_bounds__(256) void k_transpose(float* __restrict__ dst, const float* __restrict__ src, int R, int C){
  int t = blockIdx.x*256 + threadIdx.x;
  if (t >= R*C) return;
  int r = t / C, c = t - r*C;
  dst[c*R + r] = src[t];
}

// ---------------- pack fp32 [N][K] (out-major) -> f16x4 uint2 [K/4][dstStride] ----------------
__global__ __launch_bounds__(256) void k_packw(uint2* __restrict__ dst, const float* __restrict__ src,
    int N, int K, int dstStride, int colOff){
  int t = blockIdx.x*256 + threadIdx.x;
  int total = N*(K >> 2);
  if (t >= total) return;
  int o = t % N, k4 = t / N;
  const float* s = src + (size_t)o*K + 4*k4;
  __half a = __float2half_rn(s[0]), b = __float2half_rn(s[1]), c = __float2half_rn(s[2]), d = __float2half_rn(s[3]);
  unsigned x = (unsigned)(*(unsigned short*)&a) | ((unsigned)(*(unsigned short*)&b) << 16);
  unsigned y = (unsigned)(*(unsigned short*)&c) | ((unsigned)(*(unsigned short*)&d) << 16);
  dst[(size_t)k4*dstStride + colOff + o] = make_uint2(x, y);
}

// ---------------- embedding ----------------
__global__ __launch_bounds__(256) void k_embed(float* __restrict__ tE, const float* __restrict__ emb, const int* __restrict__ idx){
  int t = blockIdx.x*256 + threadIdx.x;
  int b = t >> 12, r = t & 4095, ch = r >> 5, l = r & 31;
  tE[t] = emb[idx[b*32 + l]*128 + ch];
}

// ---------------- text conv1d (k=3, pad=1) + relu ----------------
__global__ __launch_bounds__(256) void k_conv1d(const float* __restrict__ in, const float* __restrict__ w,
    const float* __restrict__ bias, float* __restrict__ out, int Cin, int Cout){
  __shared__ float inL[8192];
  int b = blockIdx.y, tid = threadIdx.x;
  int n = Cin*32;
  for (int i = tid; i < n; i += 256) inL[i] = in[(size_t)b*n + i];
  __syncthreads();
  int u = blockIdx.x*256 + tid;
  int co = u >> 2, l0 = (u & 3)*8;
  float acc[8];
  #pragma unroll
  for (int l = 0; l < 8; ++l) acc[l] = 0.f;
  for (int ci = 0; ci < Cin; ++ci){
    float rin[10];
    #pragma unroll
    for (int ii = 0; ii < 10; ++ii){
      int p = l0 - 1 + ii;
      rin[ii] = (p >= 0 && p < 32) ? inL[ci*32 + p] : 0.f;
    }
    const float* wp = w + ((size_t)co*Cin + ci)*3;
    float w0 = wp[0], w1 = wp[1], w2 = wp[2];
    #pragma unroll
    for (int l = 0; l < 8; ++l) acc[l] += rin[l]*w0 + rin[l+1]*w1 + rin[l+2]*w2;
  }
  float bb = bias ? bias[co] : 0.f;
  #pragma unroll
  for (int l = 0; l < 8; ++l){
    float v = acc[l] + bb;
    out[((size_t)b*Cout + co)*32 + l0 + l] = v > 0.f ? v : 0.f;
  }
}

// ---------------- text bn ----------------
__global__ __launch_bounds__(256) void k_bn_text(float* __restrict__ x, const float* __restrict__ g, const float* __restrict__ be, int C){
  __shared__ float s1[256], s2[256];
  __shared__ float sc[2];
  int c = blockIdx.x, tid = threadIdx.x;
  float sum = 0.f, ss = 0.f;
  for (int i = tid; i < 2048; i += 256){
    int b = i >> 5, l = i & 31;
    float v = x[((size_t)b*C + c)*32 + l];
    sum += v; ss += v*v;
  }
  s1[tid] = sum; s2[tid] = ss;
  __syncthreads();
  for (int off = 128; off; off >>= 1){
    if (tid < off){ s1[tid] += s1[tid+off]; s2[tid] += s2[tid+off]; }
    __syncthreads();
  }
  if (tid == 0){
    float mean = s1[0]*(1.f/2048.f);
    float var  = s2[0]*(1.f/2048.f) - mean*mean;
    float rs = rsqrtf(var + EPSB);
    sc[0] = g[c]*rs;
    sc[1] = be[c] - mean*g[c]*rs;
  }
  __syncthreads();
  float a = sc[0], bsh = sc[1];
  for (int i = tid; i < 2048; i += 256){
    int b = i >> 5, l = i & 31;
    size_t o = ((size_t)b*C + c)*32 + l;
    x[o] = x[o]*a + bsh;
  }
}

// ---------------- conv bn partial + finalize ----------------
__global__ __launch_bounds__(256) void k_bn_partial(const float* __restrict__ x, float* __restrict__ sums, int C, int S, int split){
  __shared__ float s1[256], s2[256];
  int c = blockIdx.x / split, chunk = blockIdx.x - c*split;
  int tid = threadIdx.x;
  int n = 64*S, per = n/split, i0 = chunk*per;
  float sum = 0.f, ss = 0.f;
  for (int i = i0 + tid; i < i0 + per; i += 256){
    int b = i / S, s = i - b*S;
    float v = x[((size_t)b*C + c)*S + s];
    sum += v; ss += v*v;
  }
  s1[tid] = sum; s2[tid] = ss;
  __syncthreads();
  for (int off = 128; off; off >>= 1){
    if (tid < off){ s1[tid] += s1[tid+off]; s2[tid] += s2[tid+off]; }
    __syncthreads();
  }
  if (tid == 0){
    atomicAdd(&sums[c], s1[0]);
    atomicAdd(&sums[C + c], s2[0]);
  }
}

__global__ void k_bn_finalize(const float* __restrict__ sums, const float* __restrict__ g, const float* __restrict__ be,
    float* __restrict__ scale, float* __restrict__ shift, int C, int S){
  int c = blockIdx.x*64 + threadIdx.x;
  if (c >= C) return;
  float n = 64.f*(float)S;
  float mean = sums[c]/n;
  float var  = sums[C+c]/n - mean*mean;
  float rs = rsqrtf(var + EPSB);
  scale[c] = g[c]*rs;
  shift[c] = be[c] - mean*g[c]*rs;
}

// ---------------- conv1 ----------------
__global__ __launch_bounds__(256) void k_conv1(const float* __restrict__ in, const float* __restrict__ wT1,
    const float* __restrict__ bias, float* __restrict__ out){
  __shared__ float tile[3888];
  int z = blockIdx.x, yq = blockIdx.y, b = blockIdx.z, tid = threadIdx.x;
  int cog = tid & 15, posg = tid >> 4;
  int yy = posg >> 2, xq = posg & 3;
  for (int i = tid; i < 3564; i += 256){
    int r = i/33, col = i - r*33;
    int ci = r/27, rr = r - 27*ci, dz = rr/9, iyl = rr - 9*dz;
    int iz = 2*z - 1 + dz;
    int iy = 8*yq - 1 + iyl;
    int ix = (col < 16) ? 2*col : 2*(col-16)-1;
    float v = 0.f;
    if (iz >= 0 && iz < 32 && iy >= 0 && ix >= 0)
      v = in[(((size_t)b*4 + ci)*32 + iz)*1024 + iy*32 + ix];
    tile[r*36 + col] = v;
  }
  __syncthreads();
  float acc[4][4];
  #pragma unroll
  for (int c = 0; c < 4; ++c){
    #pragma unroll
    for (int x = 0; x < 4; ++x) acc[c][x] = 0.f;
  }
  #pragma unroll 1
  for (int ci = 0; ci < 4; ++ci){
    #pragma unroll
    for (int dz = 0; dz < 3; ++dz){
      #pragma unroll
      for (int dy = 0; dy < 3; ++dy){
        int row = ci*972 + dz*324 + (2*yy + dy)*36;
        float4 ev = *(const float4*)&tile[row + 4*xq];
        float4 od = *(const float4*)&tile[row + 16 + 4*xq];
        float od4 = tile[row + 20 + 4*xq];
        const float* wp = wT1 + (ci*27 + dz*9 + dy*3)*64 + 4*cog;
        float4 w0 = *(const float4*)(wp);
        float4 w1 = *(const float4*)(wp + 64);
        float4 w2 = *(const float4*)(wp + 128);
        float iv0[4] = {od.x, od.y, od.z, od.w};
        float iv1[4] = {ev.x, ev.y, ev.z, ev.w};
        float iv2[4] = {od.y, od.z, od.w, od4};
        float wa0[4] = {w0.x,w0.y,w0.z,w0.w};
        float wa1[4] = {w1.x,w1.y,w1.z,w1.w};
        float wa2[4] = {w2.x,w2.y,w2.z,w2.w};
        #pragma unroll
        for (int c = 0; c < 4; ++c){
          #pragma unroll
          for (int x = 0; x < 4; ++x)
            acc[c][x] += wa0[c]*iv0[x] + wa1[c]*iv1[x] + wa2[c]*iv2[x];
        }
      }
    }
  }
  float4 bi = *(const float4*)&bias[4*cog];
  float ba[4] = {bi.x,bi.y,bi.z,bi.w};
  int y = yq*4 + yy;
  #pragma unroll
  for (int c = 0; c < 4; ++c){
    int co = 4*cog + c;
    float4 o;
    float* op = (float*)&o;
    #pragma unroll
    for (int x = 0; x < 4; ++x){
      float v = acc[c][x] + ba[c];
      op[x] = v > 0.f ? v : 0.f;
    }
    *(float4*)&out[(((size_t)b*64 + co)*16 + z)*256 + y*16 + 4*xq] = o;
  }
}

// ---------------- conv2 ----------------
__global__ __launch_bounds__(256) void k_conv2(const float* __restrict__ x1, const float* __restrict__ wT2,
    const float* __restrict__ bias, const float* __restrict__ scale, const float* __restrict__ shift,
    float* __restrict__ out){
  __shared__ float tile[16320];
  __shared__ float sclL[64], shfL[64];
  int z = blockIdx.x, coh = blockIdx.y, b = blockIdx.z, tid = threadIdx.x;
  int cog = tid & 15, posg = tid >> 4;
  int y = posg >> 1, xq = posg & 1;
  if (tid < 64){ sclL[tid] = scale[tid]; shfL[tid] = shift[tid]; }
  float acc[4][4];
  #pragma unroll
  for (int c = 0; c < 4; ++c){
    #pragma unroll
    for (int x = 0; x < 4; ++x) acc[c][x] = 0.f;
  }
  for (int ci0 = 0; ci0 < 64; ci0 += 16){
    __syncthreads();
    for (int i = tid; i < 13872; i += 256){
      int q = i/289, rem = i - q*289;
      int iyr = rem/17, col = rem - iyr*17;
      int ci = q/3, dz = q - 3*ci;
      int iz = 2*z - 1 + dz;
      int iy = iyr - 1;
      int ix = (col < 8) ? 2*col : 2*(col-8)-1;
      int cc = ci0 + ci;
      float v = 0.f;
      if (iz >= 0 && iz < 16 && iy >= 0 && ix >= 0)
        v = x1[(((size_t)b*64 + cc)*16 + iz)*256 + iy*16 + ix]*sclL[cc] + shfL[cc];
      tile[q*340 + iyr*20 + col] = v;
    }
    __syncthreads();
    #pragma unroll 1
    for (int ci = 0; ci < 16; ++ci){
      const float* wp = wT2 + ((size_t)(ci0+ci)*27)*128 + coh*64 + 4*cog;
      #pragma unroll
      for (int dz = 0; dz < 3; ++dz){
        #pragma unroll
        for (int dy = 0; dy < 3; ++dy){
          int row = ci*1020 + dz*340 + (2*y + dy)*20;
          float4 ev = *(const float4*)&tile[row + 4*xq];
          float4 od = *(const float4*)&tile[row + 8 + 4*xq];
          float od4 = tile[row + 12 + 4*xq];
          const float* wq = wp + (dz*9 + dy*3)*128;
          float4 w0 = *(const float4*)(wq);
          float4 w1 = *(const float4*)(wq + 128);
          float4 w2 = *(const float4*)(wq + 256);
          float iv0[4] = {od.x, od.y, od.z, od.w};
          float iv1[4] = {ev.x, ev.y, ev.z, ev.w};
          float iv2[4] = {od.y, od.z, od.w, od4};
          float wa0[4] = {w0.x,w0.y,w0.z,w0.w};
          float wa1[4] = {w1.x,w1.y,w1.z,w1.w};
          float wa2[4] = {w2.x,w2.y,w2.z,w2.w};
          #pragma unroll
          for (int c = 0; c < 4; ++c){
            #pragma unroll
            for (int x = 0; x < 4; ++x)
              acc[c][x] += wa0[c]*iv0[x] + wa1[c]*iv1[x] + wa2[c]*iv2[x];
          }
        }
      }
    }
  }
  float4 bi = *(const float4*)&bias[coh*64 + 4*cog];
  float ba[4] = {bi.x,bi.y,bi.z,bi.w};
  #pragma unroll
  for (int c = 0; c < 4; ++c){
    int co = coh*64 + 4*cog + c;
    float4 o;
    float* op = (float*)&o;
    #pragma unroll
    for (int x = 0; x < 4; ++x){
      float v = acc[c][x] + ba[c];
      op[x] = v > 0.f ? v : 0.f;
    }
    *(float4*)&out[(((size_t)b*128 + co)*8 + z)*64 + y*8 + 4*xq] = o;
  }
}

// ---------------- conv3 ----------------
__global__ __launch_bounds__(512) void k_conv3(const float* __restrict__ x2, const float* __restrict__ wT3,
    const float* __restrict__ bias, const float* __restrict__ scale, const float* __restrict__ shift,
    float* __restrict__ out){
  __shared__ float tile[15552];
  __shared__ float sclL[128], shfL[128];
  int coq = blockIdx.x, b = blockIdx.y, tid = threadIdx.x;
  int cog = tid & 15, posg = tid >> 4;
  int zz = posg >> 3, y = (posg >> 1) & 3, xh = posg & 1;
  if (tid < 128){ sclL[tid] = scale[tid]; shfL[tid] = shift[tid]; }
  float acc[4][2];
  #pragma unroll
  for (int c = 0; c < 4; ++c){ acc[c][0] = 0.f; acc[c][1] = 0.f; }
  for (int ci0 = 0; ci0 < 128; ci0 += 16){
    __syncthreads();
    for (int i = tid; i < 11664; i += 512){
      int ci = i/729, rem = i - ci*729;
      int izr = rem/81, rem2 = rem - izr*81;
      int iyr = rem2/9, col = rem2 - iyr*9;
      int iz = izr - 1, iy = iyr - 1;
      int ix = (col < 4) ? 2*col : 2*(col-4)-1;
      int cc = ci0 + ci;
      float v = 0.f;
      if (iz >= 0 && iy >= 0 && ix >= 0)
        v = x2[((size_t)b*128 + cc)*512 + iz*64 + iy*8 + ix]*sclL[cc] + shfL[cc];
      tile[ci*972 + izr*108 + iyr*12 + col] = v;
    }
    __syncthreads();
    #pragma unroll 1
    for (int ci = 0; ci < 16; ++ci){
      const float* wp = wT3 + ((size_t)(ci0+ci)*27)*256 + coq*64 + 4*cog;
      #pragma unroll
      for (int dz = 0; dz < 3; ++dz){
        #pragma unroll
        for (int dy = 0; dy < 3; ++dy){
          int row = ci*972 + (2*zz + dz)*108 + (2*y + dy)*12;
          float2 ev = *(const float2*)&tile[row + 2*xh];
          float2 od = *(const float2*)&tile[row + 4 + 2*xh];
          float od1 = tile[row + 6 + 2*xh];
          const float* wq = wp + (dz*9 + dy*3)*256;
          float4 w0 = *(const float4*)(wq);
          float4 w1 = *(const float4*)(wq + 256);
          float4 w2 = *(const float4*)(wq + 512);
          float iv0[2] = {od.x, od.y};
          float iv1[2] = {ev.x, ev.y};
          float iv2[2] = {od.y, od1};
          float wa0[4] = {w0.x,w0.y,w0.z,w0.w};
          float wa1[4] = {w1.x,w1.y,w1.z,w1.w};
          float wa2[4] = {w2.x,w2.y,w2.z,w2.w};
          #pragma unroll
          for (int c = 0; c < 4; ++c){
            #pragma unroll
            for (int x = 0; x < 2; ++x)
              acc[c][x] += wa0[c]*iv0[x] + wa1[c]*iv1[x] + wa2[c]*iv2[x];
          }
        }
      }
    }
  }
  float4 bi = *(const float4*)&bias[coq*64 + 4*cog];
  float ba[4] = {bi.x,bi.y,bi.z,bi.w};
  #pragma unroll
  for (int c = 0; c < 4; ++c){
    int co = coq*64 + 4*cog + c;
    float2 o;
    float v0 = acc[c][0] + ba[c], v1 = acc[c][1] + ba[c];
    o.x = v0 > 0.f ? v0 : 0.f;
    o.y = v1 > 0.f ? v1 : 0.f;
    *(float2*)&out[((size_t)b*256 + co)*64 + zz*16 + y*4 + 2*xh] = o;
  }
}

// ---------------- bn3 apply ----------------
__global__ __launch_bounds__(256) void k_bn_apply(float* __restrict__ x, const float* __restrict__ scale, const float* __restrict__ shift){
  int i = blockIdx.x*256 + threadIdx.x;
  int c = (i >> 6) & 255;
  x[i] = x[i]*scale[c] + shift[c];
}

// ---------------- x-projections ----------------
__global__ __launch_bounds__(256) void k_xproj(const float* __restrict__ tD,
    const float* __restrict__ wihT, const float* __restrict__ wxgT,
    const float* __restrict__ bih, const float* __restrict__ bhh,
    const float* __restrict__ bxg, const float* __restrict__ bhg,
    float* __restrict__ xih, float* __restrict__ xg){
  __shared__ float xr[8][256];
  int b = blockIdx.x >> 2, t0 = (blockIdx.x & 3)*8, tid = threadIdx.x;
  for (int i = tid; i < 2048; i += 256){
    int tt = i >> 8, c = i & 255;
    xr[tt][c] = tD[((size_t)b*256 + c)*32 + t0 + tt];
  }
  __syncthreads();
  float4 bi = ((const float4*)bih)[tid];
  float4 b2 = ((const float4*)bhh)[tid];
  float4 binit = make_float4(bi.x+b2.x, bi.y+b2.y, bi.z+b2.z, bi.w+b2.w);
  float4 a[8];
  #pragma unroll
  for (int tt = 0; tt < 8; ++tt) a[tt] = binit;
  const float4* Wq = (const float4*)wihT;
  for (int k = 0; k < 256; ++k){
    float4 w = Wq[k*256 + tid];
    #pragma unroll
    for (int tt = 0; tt < 8; ++tt){
      float xv = xr[tt][k];
      a[tt].x += xv*w.x; a[tt].y += xv*w.y; a[tt].z += xv*w.z; a[tt].w += xv*w.w;
    }
  }
  #pragma unroll
  for (int tt = 0; tt < 8; ++tt)
    ((float4*)xih)[((size_t)(b*32 + t0 + tt))*256 + tid] = a[tt];
  if (tid < 64){
    float4 bg = ((const float4*)bxg)[tid];
    float4 bg2 = ((const float4*)bhg)[tid];
    float4 ginit = make_float4(bg.x+bg2.x, bg.y+bg2.y, bg.z+bg2.z, bg.w+bg2.w);
    float4 g[8];
    #pragma unroll
    for (int tt = 0; tt < 8; ++tt) g[tt] = ginit;
    const float4* Wg = (const float4*)wxgT;
    for (int k = 0; k < 256; ++k){
      float4 w = Wg[k*64 + tid];
      #pragma unroll
      for (int tt = 0; tt < 8; ++tt){
        float xv = xr[tt][k];
        g[tt].x += xv*w.x; g[tt].y += xv*w.y; g[tt].z += xv*w.z; g[tt].w += xv*w.w;
      }
    }
    #pragma unroll
    for (int tt = 0; tt < 8; ++tt)
      ((float4*)xg)[((size_t)(b*32 + t0 + tt))*64 + tid] = g[tt];
  }
}

// ---------------- vproj ----------------
__global__ __launch_bounds__(512) void k_vproj(const float* __restrict__ V, const float* __restrict__ wvT,
    const float* __restrict__ bv, float* __restrict__ vproj){
  __shared__ float Vc[8][256];
  int n0 = blockIdx.x*8, b = blockIdx.y, tid = threadIdx.x;
  for (int i = tid; i < 2048; i += 512){
    int nn = i >> 8, c = i & 255;
    Vc[nn][c] = V[((size_t)b*256 + c)*64 + n0 + nn];
  }
  __syncthreads();
  float acc[8];
  float bb = bv[tid];
  #pragma unroll
  for (int nn = 0; nn < 8; ++nn) acc[nn] = bb;
  for (int k = 0; k < 256; ++k){
    float w = wvT[k*512 + tid];
    #pragma unroll
    for (int nn = 0; nn < 8; ++nn) acc[nn] += Vc[nn][k]*w;
  }
  #pragma unroll
  for (int nn = 0; nn < 8; ++nn)
    vproj[((size_t)(b*64 + n0 + nn))*512 + tid] = acc[nn];
}

// ---------------- recurrent attention scan: one block per batch row, all 1024 threads per phase ----------------
__global__ __launch_bounds__(1024) void k_scan(
    const float* __restrict__ V,
    const float* __restrict__ vproj,
    const float* __restrict__ xih,
    const float* __restrict__ xg,
    const uint2* __restrict__ WA,   // whh f16x4 [64][1024]
    const uint2* __restrict__ WG,   // whg f16x4 [64][256]
    const uint2* __restrict__ WC,   // wh | ws f16x4 [64][1024]
    const float* __restrict__ bh,
    const float* __restrict__ bs,
    const float* __restrict__ wo,
    const float* __restrict__ bo,
    const float* __restrict__ sow, const float* __restrict__ sob,
    const float* __restrict__ tow1, const float* __restrict__ tob1,
    const float* __restrict__ tow2, const float* __restrict__ tob2,
    float* __restrict__ out)
{
  __shared__ float VL[16384];                  // [n][c]
  __shared__ __align__(16) float gatesL[1024];
  __shared__ float redG[1024];
  __shared__ float bhbsL[1024];
  __shared__ float hL[256], hnewL[256], sentL[256];
  __shared__ unsigned hP[128], hnP[128], sentP[128];   // half2-packed pairs (2k, 2k+1)
  __shared__ float hpSw[528], spSw[528], woSw[528];    // swizzled [o>>5]*33 + (o&31)
  __shared__ float red[1040];                  // z partials [seg*65 + n]
  __shared__ float szred[576];                 // sz partials [(o&63)*9 + (o>>6)]
  __shared__ float wL[65];
  __shared__ float ctxmL[256], tmpL[256];

  int b = blockIdx.x, tid = threadIdx.x;
  for (int i = tid; i < 16384; i += 1024){
    int c = i >> 6, n2 = i & 63;
    VL[n2*256 + c] = V[((size_t)b*256 + c)*64 + n2];
  }
  if (tid < 512) woSw[(tid>>5)*33 + (tid&31)] = wo[tid];
  bhbsL[tid] = (tid < 512) ? bh[tid] : bs[tid-512];
  if (tid < 128) hP[tid] = 0u;
  float creg0 = 0.f, creg1 = 0.f, ctxs0 = 0.f, ctxs1 = 0.f;
  float bo0 = bo[0];
  __syncthreads();

  for (int t = 0; t < 32; ++t){
    // ---- A1: gates[o] = xih + h@whh^T, one output per thread ----
    {
      float acc = xih[((size_t)(b*32 + t))*1024 + tid];
      #pragma unroll 8
      for (int k4 = 0; k4 < 64; ++k4){
        uint2 w = WA[(size_t)k4*1024 + tid];
        acc = dot2f(w.x, hP[2*k4], acc);
        acc = dot2f(w.y, hP[2*k4+1], acc);
      }
      gatesL[tid] = acc;
    }
    // ---- A2: hg partials, 4-way split-K over 256 outputs ----
    {
      int j = tid & 255, seg4 = tid >> 8;
      float g = 0.f;
      #pragma unroll 4
      for (int i = 0; i < 16; ++i){
        int k4 = seg4*16 + i;
        uint2 w = WG[(size_t)k4*256 + j];
        g = dot2f(w.x, hP[2*k4], g);
        g = dot2f(w.y, hP[2*k4+1], g);
      }
      redG[seg4*256 + j] = g;
    }
    __syncthreads();
    // ---- B: LSTM cell elementwise; threads j<128 handle cells 2j, 2j+1; pack h_new/sent ----
    if (tid < 128){
      int j = tid;
      float2 xg2 = ((const float2*)(xg + ((size_t)(b*32 + t))*256))[j];
      const float2* rg = (const float2*)redG;
      float2 p0 = rg[j], p1 = rg[128+j], p2 = rg[256+j], p3 = rg[384+j];
      float hg0 = xg2.x + p0.x + p1.x + p2.x + p3.x;
      float hg1 = xg2.y + p0.y + p1.y + p2.y + p3.y;
      const float2* gl = (const float2*)gatesL;
      float2 gi = gl[j], gf = gl[128+j], gg = gl[256+j], go = gl[384+j];
      float i0 = fsig(gi.x), i1 = fsig(gi.y);
      float f0 = fsig(gf.x), f1 = fsig(gf.y);
      float g0 = ftanh(gg.x), g1 = ftanh(gg.y);
      float o0 = fsig(go.x), o1 = fsig(go.y);
      float c0 = f0*creg0 + i0*g0; creg0 = c0;
      float c1 = f1*creg1 + i1*g1; creg1 = c1;
      float tc0 = ftanh(c0), tc1 = ftanh(c1);
      float hn0 = o0*tc0, hn1 = o1*tc1;
      float s0 = fsig(hg0)*tc0, s1 = fsig(hg1)*tc1;
      hnewL[2*j] = hn0; hnewL[2*j+1] = hn1;
      sentL[2*j] = s0;  sentL[2*j+1] = s1;
      __half2 ph = __floats2half2_rn(hn0, hn1); hnP[j] = *(unsigned*)&ph;
      __half2 ps = __floats2half2_rn(s0, s1);   sentP[j] = *(unsigned*)&ps;
    }
    __syncthreads();
    // ---- C: hp (o<512, from h_new) | sp (o>=512, from sent), one output per thread ----
    {
      int o = tid;
      float acc = bhbsL[o];
      const unsigned* hs = (o < 512) ? hnP : sentP;
      #pragma unroll 8
      for (int k4 = 0; k4 < 64; ++k4){
        uint2 w = WC[(size_t)k4*1024 + o];
        acc = dot2f(w.x, hs[2*k4], acc);
        acc = dot2f(w.y, hs[2*k4+1], acc);
      }
      int oo = o & 511;
      int r = (oo>>5)*33 + (oo&31);
      if (o < 512) hpSw[r] = acc; else spSw[r] = acc;
    }
    __syncthreads();
    // ---- D: z partials (n x 16 segs) + sz partials ----
    {
      int n2 = tid >> 4, seg = tid & 15;
      const float4* vp4 = (const float4*)(vproj + ((size_t)(b*64 + n2))*512 + seg*32);
      float a = 0.f;
      #pragma unroll
      for (int q = 0; q < 8; ++q){
        float4 v = vp4[q];
        int r = seg*33 + 4*q;
        a += ftanh(v.x + hpSw[r  ])*woSw[r  ];
        a += ftanh(v.y + hpSw[r+1])*woSw[r+1];
        a += ftanh(v.z + hpSw[r+2])*woSw[r+2];
        a += ftanh(v.w + hpSw[r+3])*woSw[r+3];
      }
      red[seg*65 + n2] = a;
      if (tid < 512){
        int r = (tid>>5)*33 + (tid&31);
        szred[(tid&63)*9 + (tid>>6)] = ftanh(spSw[r] + hpSw[r])*woSw[r];
      }
    }
    __syncthreads();
    // ---- E: fold + softmax over 65 (wave 0) ----
    if (tid < 64){
      float zi = bo0;
      #pragma unroll
      for (int i = 0; i < 16; ++i) zi += red[i*65 + tid];
      float szp = 0.f;
      #pragma unroll
      for (int i = 0; i < 8; ++i) szp += szred[tid*9 + i];
      #pragma unroll
      for (int off = 32; off; off >>= 1) szp += __shfl_xor(szp, off, 64);
      float sz = szp + bo0;
      float m = zi;
      #pragma unroll
      for (int off = 32; off; off >>= 1) m = fmaxf(m, __shfl_xor(m, off, 64));
      m = fmaxf(m, sz);
      float e = __expf(zi - m);
      float s = e;
      #pragma unroll
      for (int off = 32; off; off >>= 1) s += __shfl_xor(s, off, 64);
      float esz = __expf(sz - m);
      float denom = s + esz;
      wL[tid] = e/denom;
      if (tid == 0) wL[64] = esz/denom;
    }
    __syncthreads();
    // ---- F: attended + new h (threads j<128, cells 2j, 2j+1) ----
    if (tid < 128){
      int j = tid;
      float a0 = 0.f, a1 = 0.f;
      #pragma unroll 4
      for (int n = 0; n < 64; ++n){
        float2 v = *(const float2*)&VL[n*256 + 2*j];
        float wn = wL[n];
        a0 += v.x*wn; a1 += v.y*wn;
      }
      float beta = wL[64];
      float ctx0 = (1.f - beta)*a0, ctx1 = (1.f - beta)*a1;
      ctxs0 += ctx0; ctxs1 += ctx1;
      float h0 = beta*sentL[2*j] + ctx0 + hnewL[2*j];
      float h1 = beta*sentL[2*j+1] + ctx1 + hnewL[2*j+1];
      hL[2*j] = h0; hL[2*j+1] = h1;
      __half2 ph = __floats2half2_rn(h0, h1); hP[j] = *(unsigned*)&ph;
    }
    __syncthreads();
  }
  // ---- epilogue: heads ----
  if (tid < 128){ ctxmL[2*tid] = ctxs0*(1.f/32.f); ctxmL[2*tid+1] = ctxs1*(1.f/32.f); }
  __syncthreads();
  if (tid < 256){
    float a = tob1[tid];
    const float* w = tow1 + (size_t)tid*256;
    #pragma unroll 4
    for (int c = 0; c < 256; ++c) a += hL[c]*w[c];
    tmpL[tid] = a > 0.f ? a : 0.f;
  }
  __syncthreads();
  if (tid < 128){
    float s = sob[tid];
    const float* w = sow + (size_t)tid*256;
    #pragma unroll 4
    for (int c = 0; c < 256; ++c) s += ctxmL[c]*w[c];
    out[b*128 + tid] = s;
    float tx = tob2[tid];
    const float* w2 = tow2 + (size_t)tid*256;
    #pragma unroll 4
    for (int k = 0; k < 256; ++k) tx += tmpL[k]*w2[k];
    out[8192 + b*128 + tid] = tx;
  }
}

extern "C" void kernel_launch(void* const* d_in, const int* in_sizes, int n_in,
                              void* d_out, int out_size, void* d_ws, size_t ws_size,
                              hipStream_t stream){
  const float* shape_in = (const float*)d_in[0];
  const int*   text_in  = (const int*)d_in[1];
  const float* c1w = (const float*)d_in[2];
  const float* c1b = (const float*)d_in[3];
  const float* g1  = (const float*)d_in[4];
  const float* be1 = (const float*)d_in[5];
  const float* c2w = (const float*)d_in[6];
  const float* c2b = (const float*)d_in[7];
  const float* g2  = (const float*)d_in[8];
  const float* be2 = (const float*)d_in[9];
  const float* c3w = (const float*)d_in[10];
  const float* c3b = (const float*)d_in[11];
  const float* g3  = (const float*)d_in[12];
  const float* be3 = (const float*)d_in[13];
  const float* sow = (const float*)d_in[14];
  const float* sob = (const float*)d_in[15];
  const float* emb = (const float*)d_in[16];
  const float* t1w = (const float*)d_in[17];
  const float* t1b = (const float*)d_in[18];
  const float* t2w = (const float*)d_in[19];
  const float* g128= (const float*)d_in[20];
  const float* b128= (const float*)d_in[21];
  const float* t3w = (const float*)d_in[22];
  const float* t3b = (const float*)d_in[23];
  const float* t4w = (const float*)d_in[24];
  const float* g256= (const float*)d_in[25];
  const float* b256= (const float*)d_in[26];
  const float* tow1= (const float*)d_in[27];
  const float* tob1= (const float*)d_in[28];
  const float* tow2= (const float*)d_in[29];
  const float* tob2= (const float*)d_in[30];
  const float* wih = (const float*)d_in[31];
  const float* whh = (const float*)d_in[32];
  const float* bih = (const float*)d_in[33];
  const float* bhh = (const float*)d_in[34];
  const float* wxg = (const float*)d_in[35];
  const float* bxg = (const float*)d_in[36];
  const float* whg = (const float*)d_in[37];
  const float* bhg = (const float*)d_in[38];
  const float* wv  = (const float*)d_in[39];
  const float* bv  = (const float*)d_in[40];
  const float* wh  = (const float*)d_in[41];
  const float* bh  = (const float*)d_in[42];
  const float* wsw = (const float*)d_in[43];
  const float* bsb = (const float*)d_in[44];
  const float* wo  = (const float*)d_in[45];
  const float* bo  = (const float*)d_in[46];
  float* out = (float*)d_out;
  float* Wk = (float*)d_ws;

  if (ws_size < (size_t)24905088*4) return;

  float* x1     = Wk + 0;           // 64*64*4096 (dead after conv2)
  float* xih    = Wk + 0;           // reuses x1 region (after conv2)
  float* xg     = Wk + 2097152;
  float* vproj  = Wk + 2621440;
  float* wT3_   = Wk + 4718592;     // 884736 fl; written after conv2 (x1 dead)
  float* x2     = Wk + 16777216;    // 64*128*512
  float* wT1_   = Wk + 16777216;    // dead before conv2 writes x2
  float* Vb     = Wk + 20971520;    // 64*256*64
  float* wT2_   = Wk + 20971520;    // dead before conv3 writes Vb
  float* tE     = Wk + 22020096;
  float* tA     = Wk + 22282240;
  float* tB     = Wk + 22544384;
  float* tC     = Wk + 22806528;
  float* tD     = Wk + 23330816;
  uint2* WA_    = (uint2*)(Wk + 23855104);   // 65536 uint2 = 131072 fl
  uint2* WG_    = (uint2*)(Wk + 23986176);   // 16384 uint2 = 32768 fl
  uint2* WC_    = (uint2*)(Wk + 24018944);   // 65536 uint2 = 131072 fl
  float* wvT_   = Wk + 24444928;
  float* wihT_  = Wk + 24576000;
  float* wxgT_  = Wk + 24838144;
  float* scale1 = Wk + 24903680;
  float* shift1 = scale1 + 64;
  float* scale2 = shift1 + 64;
  float* shift2 = scale2 + 128;
  float* scale3 = shift2 + 128;
  float* shift3 = scale3 + 256;
  float* sums   = shift3 + 256;

  // scan weight packs (f16x4) + remaining fp32 transposes
  k_packw<<<256,256,0,stream>>>(WA_, whh, 1024, 256, 1024, 0);
  k_packw<<<64, 256,0,stream>>>(WG_, whg, 256, 256, 256, 0);
  k_packw<<<128,256,0,stream>>>(WC_, wh,  512, 256, 1024, 0);
  k_packw<<<128,256,0,stream>>>(WC_, wsw, 512, 256, 1024, 512);
  k_transpose<<<512, 256,0,stream>>>(wvT_,  wv,  512, 256);
  k_transpose<<<1024,256,0,stream>>>(wihT_, wih, 1024, 256);
  k_transpose<<<256, 256,0,stream>>>(wxgT_, wxg, 256, 256);
  k_transpose<<<27,  256,0,stream>>>(wT1_,  c1w, 64, 108);
  k_transpose<<<864, 256,0,stream>>>(wT2_,  c2w, 128, 1728);

  // text branch
  k_embed<<<1024,256,0,stream>>>(tE, emb, text_in);
  k_conv1d<<<dim3(2,64),256,0,stream>>>(tE, t1w, t1b, tA, 128, 128);
  k_conv1d<<<dim3(2,64),256,0,stream>>>(tA, t2w, nullptr, tB, 128, 128);
  k_bn_text<<<128,256,0,stream>>>(tB, g128, b128, 128);
  k_conv1d<<<dim3(4,64),256,0,stream>>>(tB, t3w, t3b, tC, 128, 256);
  k_conv1d<<<dim3(4,64),256,0,stream>>>(tC, t4w, nullptr, tD, 256, 256);
  k_bn_text<<<256,256,0,stream>>>(tD, g256, b256, 256);

  // conv1 + bn1 stats
  k_conv1<<<dim3(16,4,64),256,0,stream>>>(shape_in, wT1_, c1b, x1);
  hipMemsetAsync(sums, 0, 2*64*sizeof(float), stream);
  k_bn_partial<<<64*16,256,0,stream>>>(x1, sums, 64, 4096, 16);
  k_bn_finalize<<<1,64,0,stream>>>(sums, g1, be1, scale1, shift1, 64, 4096);

  // conv2 + bn2 stats
  k_conv2<<<dim3(8,2,64),256,0,stream>>>(x1, wT2_, c2b, scale1, shift1, x2);
  hipMemsetAsync(sums, 0, 2*128*sizeof(float), stream);
  k_bn_partial<<<128*8,256,0,stream>>>(x2, sums, 128, 512, 8);
  k_bn_finalize<<<2,64,0,stream>>>(sums, g2, be2, scale2, shift2, 128, 512);

  // x-projections (x1 region now dead -> xih/xg)
  k_xproj<<<256,256,0,stream>>>(tD, wihT_, wxgT_, bih, bhh, bxg, bhg, xih, xg);

  // conv3 weight layout (into dead region), then conv3 + bn3
  k_transpose<<<3456,256,0,stream>>>(wT3_, c3w, 256, 3456);
  k_conv3<<<dim3(4,64),512,0,stream>>>(x2, wT3_, c3b, scale2, shift2, Vb);
  hipMemsetAsync(sums, 0, 2*256*sizeof(float), stream);
  k_bn_partial<<<256*2,256,0,stream>>>(Vb, sums, 256, 64, 2);
  k_bn_finalize<<<4,64,0,stream>>>(sums, g3, be3, scale3, shift3, 256, 64);
  k_bn_apply<<<4096,256,0,stream>>>(Vb, scale3, shift3);

  // vproj
  k_vproj<<<dim3(8,64),512,0,stream>>>(Vb, wvT_, bv, vproj);

  // scan + fused heads
  k_scan<<<64,1024,0,stream>>>(Vb, vproj, xih, xg, WA_, WG_, WC_,
                               bh, bsb, wo, bo, sow, sob, tow1, tob1, tow2, tob2, out);
}